// Round 1
// baseline (135.601 us; speedup 1.0000x reference)
//
#include <hip/hip_runtime.h>

typedef unsigned short u16;
typedef __bf16 bf16x8 __attribute__((ext_vector_type(8)));
typedef float  f32x4  __attribute__((ext_vector_type(4)));
typedef unsigned int   u32x4 __attribute__((ext_vector_type(4)));
typedef unsigned short u16x4 __attribute__((ext_vector_type(4)));

#define DEV __device__ __forceinline__

#define NB   16
#define TT   512
#define DD   256
#define HH   4
#define DKH  64
#define NLANG 10
#define FFD  1024

DEV u16 f2bf(float f) {
  unsigned int u = __builtin_bit_cast(unsigned int, f);
  return (u16)((u + 0x7fffu + ((u >> 16) & 1u)) >> 16);
}

DEV f32x4 zero4() { f32x4 z; z[0]=0.f; z[1]=0.f; z[2]=0.f; z[3]=0.f; return z; }

// ---------------- weight transpose + fp32->bf16 convert ----------------
// src: (z, R, C) f32   dst: (z, C, R) bf16   (dst[c][r] = src[r][c])
__global__ __launch_bounds__(256) void tconv_kernel(const float* __restrict__ src,
                                                    u16* __restrict__ dst,
                                                    int R, int C) {
  __shared__ u16 tile[32][33];
  const int z = blockIdx.z;
  const float* s = src + (size_t)z * R * C;
  u16* d = dst + (size_t)z * R * C;
  const int r0 = blockIdx.x * 32, c0 = blockIdx.y * 32;
  const int tx = threadIdx.x & 31, ty = threadIdx.x >> 5;  // ty in [0,8)
#pragma unroll
  for (int rr = 0; rr < 4; ++rr) {
    int r = ty + rr * 8;
    tile[r][tx] = f2bf(s[(size_t)(r0 + r) * C + c0 + tx]);
  }
  __syncthreads();
#pragma unroll
  for (int rr = 0; rr < 4; ++rr) {
    int cc = ty + rr * 8;
    d[(size_t)(c0 + cc) * R + r0 + tx] = tile[tx][cc];
  }
}

// ---------------- embed (x*sqrt(D)+PE) + LN1 ----------------
__global__ __launch_bounds__(256) void embed_ln_kernel(const float* __restrict__ x,
                                                       float* __restrict__ h0,
                                                       u16* __restrict__ hn,
                                                       const float* __restrict__ g,
                                                       const float* __restrict__ be,
                                                       const int* __restrict__ lids) {
  const int wave = threadIdx.x >> 6, lane = threadIdx.x & 63;
  const int row = blockIdx.x * 4 + wave;      // [0, 8192)
  const int b = row >> 9, t = row & 511;
  const int z = lids[b];
  const int c0 = lane * 4;
  const float4 xv = *(const float4*)(x + (size_t)row * DD + c0);
  const float kPE = -9.21034037197618f / 256.0f;  // -ln(10000)/D
  float div0 = __expf(kPE * (float)c0);
  float div1 = __expf(kPE * (float)(c0 + 2));
  float a0 = div0 * (float)t, a1 = div1 * (float)t;
  float h[4];
  h[0] = xv.x * 16.0f + sinf(a0);
  h[1] = xv.y * 16.0f + cosf(a0);
  h[2] = xv.z * 16.0f + sinf(a1);
  h[3] = xv.w * 16.0f + cosf(a1);
  float s = h[0] + h[1] + h[2] + h[3];
  float ss = h[0]*h[0] + h[1]*h[1] + h[2]*h[2] + h[3]*h[3];
#pragma unroll
  for (int d = 1; d < 64; d <<= 1) { s += __shfl_xor(s, d); ss += __shfl_xor(ss, d); }
  float mean = s * (1.0f / 256.0f);
  float var  = ss * (1.0f / 256.0f) - mean * mean;
  float rstd = rsqrtf(var + 1e-12f);
  *(float4*)(h0 + (size_t)row * DD + c0) = make_float4(h[0], h[1], h[2], h[3]);
  u16x4 o;
#pragma unroll
  for (int j = 0; j < 4; ++j)
    o[j] = f2bf((h[j] - mean) * rstd * g[z * DD + c0 + j] + be[z * DD + c0 + j]);
  *(u16x4*)(hn + (size_t)row * DD + c0) = o;
}

// ---------------- generic LN (f32 in; bf16 or f32 out) ----------------
template<int OUTF32>
__global__ __launch_bounds__(256) void ln_kernel(const float* __restrict__ in,
                                                 void* __restrict__ outp,
                                                 const float* __restrict__ g,
                                                 const float* __restrict__ be,
                                                 const int* __restrict__ lids) {
  const int wave = threadIdx.x >> 6, lane = threadIdx.x & 63;
  const int row = blockIdx.x * 4 + wave;
  const int b = row >> 9;
  const int z = lids[b];
  const int c0 = lane * 4;
  const float4 v = *(const float4*)(in + (size_t)row * DD + c0);
  float h[4] = {v.x, v.y, v.z, v.w};
  float s = h[0] + h[1] + h[2] + h[3];
  float ss = h[0]*h[0] + h[1]*h[1] + h[2]*h[2] + h[3]*h[3];
#pragma unroll
  for (int d = 1; d < 64; d <<= 1) { s += __shfl_xor(s, d); ss += __shfl_xor(ss, d); }
  float mean = s * (1.0f / 256.0f);
  float var  = ss * (1.0f / 256.0f) - mean * mean;
  float rstd = rsqrtf(var + 1e-12f);
  if (OUTF32) {
    float4 o;
    o.x = (h[0] - mean) * rstd * g[z * DD + c0 + 0] + be[z * DD + c0 + 0];
    o.y = (h[1] - mean) * rstd * g[z * DD + c0 + 1] + be[z * DD + c0 + 1];
    o.z = (h[2] - mean) * rstd * g[z * DD + c0 + 2] + be[z * DD + c0 + 2];
    o.w = (h[3] - mean) * rstd * g[z * DD + c0 + 3] + be[z * DD + c0 + 3];
    *(float4*)((float*)outp + (size_t)row * DD + c0) = o;
  } else {
    u16x4 o;
#pragma unroll
    for (int j = 0; j < 4; ++j)
      o[j] = f2bf((h[j] - mean) * rstd * g[z * DD + c0 + j] + be[z * DD + c0 + j]);
    *(u16x4*)((u16*)outp + (size_t)row * DD + c0) = o;
  }
}

// ---------------- GEMM core: C(128x128) = A(128xK) @ W^T(128xK)^T ----------------
// A: batch base, row stride K (bf16). W: lang base, N rows x K cols (bf16, = W^T).
DEV void gemm_tile(const u16* __restrict__ A, const u16* __restrict__ W, int K,
                   int m0, int n0, u16* Alds, u16* Blds, f32x4 acc[4][4]) {
  const int tid = threadIdx.x;
  const int lane = tid & 63;
  const int wave = tid >> 6;
  const int wm = wave >> 1, wn = wave & 1;
  const int l15 = lane & 15, lhi = lane >> 4;
  const int srow = tid >> 3;          // [0,32)
  const int sc8 = (tid & 7) << 3;     // 0..56
  for (int k0 = 0; k0 < K; k0 += 64) {
#pragma unroll
    for (int it = 0; it < 4; ++it) {
      int r = srow + it * 32;
      *(u32x4*)(Alds + r * 72 + sc8) = *(const u32x4*)(A + (size_t)(m0 + r) * K + k0 + sc8);
      *(u32x4*)(Blds + r * 72 + sc8) = *(const u32x4*)(W + (size_t)(n0 + r) * K + k0 + sc8);
    }
    __syncthreads();
#pragma unroll
    for (int ks = 0; ks < 2; ++ks) {
      const int kk = ks * 32 + lhi * 8;
      bf16x8 af[4], bfr[4];
#pragma unroll
      for (int m = 0; m < 4; ++m)
        af[m] = *(const bf16x8*)(Alds + (wm * 64 + m * 16 + l15) * 72 + kk);
#pragma unroll
      for (int n = 0; n < 4; ++n)
        bfr[n] = *(const bf16x8*)(Blds + (wn * 64 + n * 16 + l15) * 72 + kk);
#pragma unroll
      for (int m = 0; m < 4; ++m)
#pragma unroll
        for (int n = 0; n < 4; ++n)
          acc[m][n] = __builtin_amdgcn_mfma_f32_16x16x32_bf16(af[m], bfr[n], acc[m][n], 0, 0, 0);
    }
    __syncthreads();
  }
}

// EPI: 0 = bf16 out (+bias), 1 = bf16 out (+bias, relu), 2 = f32 out = res + acc + bias
template<int EPI>
__global__ __launch_bounds__(256) void gemm_kernel(const u16* __restrict__ A,
                                                   const u16* __restrict__ Wt,
                                                   const float* __restrict__ bias,
                                                   const float* __restrict__ res,
                                                   void* __restrict__ outp,
                                                   const int* __restrict__ lids,
                                                   int N, int K) {
  __shared__ u16 Alds[128 * 72];
  __shared__ u16 Blds[128 * 72];
  const int b = blockIdx.z;
  const int z = lids[b];
  const int m0 = blockIdx.y * 128, n0 = blockIdx.x * 128;
  f32x4 acc[4][4];
#pragma unroll
  for (int i = 0; i < 4; ++i)
#pragma unroll
    for (int j = 0; j < 4; ++j) acc[i][j] = zero4();
  gemm_tile(A + (size_t)b * TT * K, Wt + (size_t)z * N * K, K, m0, n0, Alds, Blds, acc);
  const int lane = threadIdx.x & 63, wave = threadIdx.x >> 6;
  const int wm = wave >> 1, wn = wave & 1;
  const int l15 = lane & 15, lhi = lane >> 4;
  float bvv[4];
#pragma unroll
  for (int n = 0; n < 4; ++n) bvv[n] = bias[(size_t)z * N + n0 + wn * 64 + n * 16 + l15];
#pragma unroll
  for (int m = 0; m < 4; ++m) {
    const int grow = m0 + wm * 64 + m * 16 + lhi * 4;
#pragma unroll
    for (int n = 0; n < 4; ++n) {
      const int gcol = n0 + wn * 64 + n * 16 + l15;
#pragma unroll
      for (int r = 0; r < 4; ++r) {
        float v = acc[m][n][r] + bvv[n];
        size_t idx = (size_t)b * TT * N + (size_t)(grow + r) * N + gcol;
        if (EPI == 0) ((u16*)outp)[idx] = f2bf(v);
        else if (EPI == 1) ((u16*)outp)[idx] = f2bf(v > 0.f ? v : 0.f);
        else ((float*)outp)[idx] = res[idx] + v;
      }
    }
  }
}

// QKV fused: grid (2,4,48). which = z>>4 selects Q/K/V; V stored transposed (B,H,DK,T).
__global__ __launch_bounds__(256) void gemm_qkv(const u16* __restrict__ A,
                                                const u16* __restrict__ wtq,
                                                const u16* __restrict__ wtk,
                                                const u16* __restrict__ wtv,
                                                const float* __restrict__ bq,
                                                const float* __restrict__ bk,
                                                const float* __restrict__ bv,
                                                u16* __restrict__ qo,
                                                u16* __restrict__ ko,
                                                u16* __restrict__ vto,
                                                const int* __restrict__ lids) {
  __shared__ u16 Alds[128 * 72];
  __shared__ u16 Blds[128 * 72];
  const int b = blockIdx.z & 15, which = blockIdx.z >> 4;
  const int z = lids[b];
  const u16* W = (which == 0) ? wtq : (which == 1) ? wtk : wtv;
  const float* bias = (which == 0) ? bq : (which == 1) ? bk : bv;
  const int m0 = blockIdx.y * 128, n0 = blockIdx.x * 128;
  f32x4 acc[4][4];
#pragma unroll
  for (int i = 0; i < 4; ++i)
#pragma unroll
    for (int j = 0; j < 4; ++j) acc[i][j] = zero4();
  gemm_tile(A + (size_t)b * TT * DD, W + (size_t)z * DD * DD, DD, m0, n0, Alds, Blds, acc);
  const int lane = threadIdx.x & 63, wave = threadIdx.x >> 6;
  const int wm = wave >> 1, wn = wave & 1;
  const int l15 = lane & 15, lhi = lane >> 4;
  float bvv[4];
#pragma unroll
  for (int n = 0; n < 4; ++n) bvv[n] = bias[(size_t)z * DD + n0 + wn * 64 + n * 16 + l15];
  if (which < 2) {
    u16* out = (which == 0) ? qo : ko;
#pragma unroll
    for (int m = 0; m < 4; ++m) {
      const int grow = m0 + wm * 64 + m * 16 + lhi * 4;
#pragma unroll
      for (int n = 0; n < 4; ++n) {
        const int gcol = n0 + wn * 64 + n * 16 + l15;
#pragma unroll
        for (int r = 0; r < 4; ++r)
          out[(size_t)b * TT * DD + (size_t)(grow + r) * DD + gcol] = f2bf(acc[m][n][r] + bvv[n]);
      }
    }
  } else {
#pragma unroll
    for (int m = 0; m < 4; ++m) {
      const int grow = m0 + wm * 64 + m * 16 + lhi * 4;  // t, multiple of 4
#pragma unroll
      for (int n = 0; n < 4; ++n) {
        const int gcol = n0 + wn * 64 + n * 16 + l15;    // feature = h*64+dk
        u16x4 pk;
#pragma unroll
        for (int r = 0; r < 4; ++r) pk[r] = f2bf(acc[m][n][r] + bvv[n]);
        *(u16x4*)(vto + (size_t)(b * HH + (gcol >> 6)) * DKH * TT + (size_t)(gcol & 63) * TT + grow) = pk;
      }
    }
  }
}

// ---------------- attention: block = (qtile of 64 rows, head, batch) ----------------
__global__ __launch_bounds__(256) void attn_kernel(const u16* __restrict__ q,
                                                   const u16* __restrict__ k,
                                                   const u16* __restrict__ vt,
                                                   u16* __restrict__ ctx,
                                                   const int* __restrict__ lens) {
  __shared__ u16 Plds[64 * 512];  // 64KB, XOR-swizzled by row%16
  const int qt = blockIdx.x, h = blockIdx.y, b = blockIdx.z;
  const int lane = threadIdx.x & 63, wave = threadIdx.x >> 6;
  const int l15 = lane & 15, lhi = lane >> 4;
  const int len = lens[b];
  const int qrow0 = qt * 64 + wave * 16;
  const u16* qb = q + (size_t)b * TT * DD + h * DKH;
  const u16* kb = k + (size_t)b * TT * DD + h * DKH;

  // ---- phase 1: S = Q K^T / 8, masked softmax (unnormalized P -> LDS) ----
  bf16x8 qf[2];
#pragma unroll
  for (int ks = 0; ks < 2; ++ks)
    qf[ks] = *(const bf16x8*)(qb + (size_t)(qrow0 + l15) * DD + ks * 32 + lhi * 8);
  f32x4 s[32];
#pragma unroll
  for (int nb = 0; nb < 32; ++nb) {
    f32x4 a = zero4();
#pragma unroll
    for (int ks = 0; ks < 2; ++ks) {
      bf16x8 kf = *(const bf16x8*)(kb + (size_t)(nb * 16 + l15) * DD + ks * 32 + lhi * 8);
      a = __builtin_amdgcn_mfma_f32_16x16x32_bf16(qf[ks], kf, a, 0, 0, 0);
    }
    s[nb] = a;
  }
  float mr[4] = {-1e30f, -1e30f, -1e30f, -1e30f};
#pragma unroll
  for (int nb = 0; nb < 32; ++nb) {
    const int col = nb * 16 + l15;
#pragma unroll
    for (int r = 0; r < 4; ++r) {
      float v = s[nb][r] * 0.125f;
      v = (col < len) ? v : -1e30f;
      s[nb][r] = v;
      mr[r] = fmaxf(mr[r], v);
    }
  }
#pragma unroll
  for (int d = 1; d < 16; d <<= 1)
#pragma unroll
    for (int r = 0; r < 4; ++r) mr[r] = fmaxf(mr[r], __shfl_xor(mr[r], d));
  float lr[4] = {0.f, 0.f, 0.f, 0.f};
#pragma unroll
  for (int nb = 0; nb < 32; ++nb) {
    const int col = nb * 16 + l15;
#pragma unroll
    for (int r = 0; r < 4; ++r) {
      float p = (col < len) ? __expf(s[nb][r] - mr[r]) : 0.f;
      lr[r] += p;
      const int lrow = wave * 16 + lhi * 4 + r;
      Plds[lrow * 512 + (col ^ ((lrow & 15) << 3))] = f2bf(p);
    }
  }
#pragma unroll
  for (int d = 1; d < 16; d <<= 1)
#pragma unroll
    for (int r = 0; r < 4; ++r) lr[r] += __shfl_xor(lr[r], d);
  __syncthreads();

  // ---- phase 2: O = P @ V (V^T layout: (b,h,dk,t)), then scale by 1/l ----
  const u16* vtb = vt + (size_t)(b * HH + h) * DKH * TT;
  f32x4 o[4];
#pragma unroll
  for (int d0 = 0; d0 < 4; ++d0) o[d0] = zero4();
  const int arow = wave * 16 + l15;
#pragma unroll
  for (int ks = 0; ks < 16; ++ks) {
    bf16x8 pf = *(const bf16x8*)(Plds + arow * 512 + ((ks * 32 + lhi * 8) ^ ((arow & 15) << 3)));
#pragma unroll
    for (int d0 = 0; d0 < 4; ++d0) {
      bf16x8 vf = *(const bf16x8*)(vtb + (size_t)(d0 * 16 + l15) * TT + ks * 32 + lhi * 8);
      o[d0] = __builtin_amdgcn_mfma_f32_16x16x32_bf16(pf, vf, o[d0], 0, 0, 0);
    }
  }
  float inv[4];
#pragma unroll
  for (int r = 0; r < 4; ++r) inv[r] = 1.0f / lr[r];
  u16* cb = ctx + (size_t)b * TT * DD + h * DKH;
#pragma unroll
  for (int d0 = 0; d0 < 4; ++d0)
#pragma unroll
    for (int r = 0; r < 4; ++r)
      cb[(size_t)(qrow0 + lhi * 4 + r) * DD + d0 * 16 + l15] = f2bf(o[d0][r] * inv[r]);
}

// ---------------- host ----------------
extern "C" void kernel_launch(void* const* d_in, const int* in_sizes, int n_in,
                              void* d_out, int out_size, void* d_ws, size_t ws_size,
                              hipStream_t stream) {
  (void)in_sizes; (void)n_in; (void)out_size; (void)ws_size;
  const float* x    = (const float*)d_in[0];
  const int*   xlen = (const int*)d_in[1];
  const int*   lids = (const int*)d_in[2];
  const float* Wq = (const float*)d_in[3];
  const float* bq = (const float*)d_in[4];
  const float* Wk = (const float*)d_in[5];
  const float* bk = (const float*)d_in[6];
  const float* Wv = (const float*)d_in[7];
  const float* bv = (const float*)d_in[8];
  const float* Wo = (const float*)d_in[9];
  const float* bo = (const float*)d_in[10];
  const float* W1 = (const float*)d_in[11];
  const float* b1 = (const float*)d_in[12];
  const float* W2 = (const float*)d_in[13];
  const float* b2 = (const float*)d_in[14];
  const float* g1 = (const float*)d_in[15];
  const float* be1= (const float*)d_in[16];
  const float* g2 = (const float*)d_in[17];
  const float* be2= (const float*)d_in[18];
  const float* gf = (const float*)d_in[19];
  const float* bef= (const float*)d_in[20];

  char* ws = (char*)d_ws;
  size_t off = 0;
  auto alloc = [&](size_t bytes) -> void* {
    void* p = ws + off;
    off = (off + bytes + 255) & ~(size_t)255;
    return p;
  };
  u16* wtq = (u16*)alloc((size_t)NLANG * DD * DD * 2);
  u16* wtk = (u16*)alloc((size_t)NLANG * DD * DD * 2);
  u16* wtv = (u16*)alloc((size_t)NLANG * DD * DD * 2);
  u16* wto = (u16*)alloc((size_t)NLANG * DD * DD * 2);
  u16* wt1 = (u16*)alloc((size_t)NLANG * DD * FFD * 2);
  u16* wt2 = (u16*)alloc((size_t)NLANG * FFD * DD * 2);
  float* h0 = (float*)alloc((size_t)NB * TT * DD * 4);
  float* hc = (float*)alloc((size_t)NB * TT * DD * 4);
  u16* hn  = (u16*)alloc((size_t)NB * TT * DD * 2);
  u16* qb  = (u16*)alloc((size_t)NB * TT * DD * 2);
  u16* kb  = (u16*)alloc((size_t)NB * TT * DD * 2);
  u16* vtb = (u16*)alloc((size_t)NB * TT * DD * 2);
  u16* ctx = (u16*)alloc((size_t)NB * TT * DD * 2);
  u16* ffn = (u16*)alloc((size_t)NB * TT * FFD * 2);

  // weights -> bf16 transposed (N x K)
  tconv_kernel<<<dim3(8, 8, NLANG), 256, 0, stream>>>(Wq, wtq, DD, DD);
  tconv_kernel<<<dim3(8, 8, NLANG), 256, 0, stream>>>(Wk, wtk, DD, DD);
  tconv_kernel<<<dim3(8, 8, NLANG), 256, 0, stream>>>(Wv, wtv, DD, DD);
  tconv_kernel<<<dim3(8, 8, NLANG), 256, 0, stream>>>(Wo, wto, DD, DD);
  tconv_kernel<<<dim3(8, 32, NLANG), 256, 0, stream>>>(W1, wt1, DD, FFD);
  tconv_kernel<<<dim3(32, 8, NLANG), 256, 0, stream>>>(W2, wt2, FFD, DD);

  // h0 = x*16 + PE ; hn = LN1(h0)
  embed_ln_kernel<<<dim3(NB * TT / 4), 256, 0, stream>>>(x, h0, hn, g1, be1, lids);

  // QKV
  gemm_qkv<<<dim3(2, 4, 48), 256, 0, stream>>>(hn, wtq, wtk, wtv, bq, bk, bv, qb, kb, vtb, lids);

  // attention
  attn_kernel<<<dim3(8, HH, NB), 256, 0, stream>>>(qb, kb, vtb, ctx, xlen);

  // h = h0 + ctx @ Wo + bo
  gemm_kernel<2><<<dim3(2, 4, NB), 256, 0, stream>>>(ctx, wto, bo, h0, hc, lids, DD, DD);

  // hn = LN2(h)
  ln_kernel<0><<<dim3(NB * TT / 4), 256, 0, stream>>>(hc, hn, g2, be2, lids);

  // ffn = relu(hn @ W1 + b1)
  gemm_kernel<1><<<dim3(8, 4, NB), 256, 0, stream>>>(hn, wt1, b1, nullptr, ffn, lids, FFD, DD);

  // h = h + ffn @ W2 + b2   (in-place residual)
  gemm_kernel<2><<<dim3(2, 4, NB), 256, 0, stream>>>(ffn, wt2, b2, hc, hc, lids, DD, FFD);

  // out = LNf(h)
  ln_kernel<1><<<dim3(NB * TT / 4), 256, 0, stream>>>(hc, d_out, gf, bef, lids);
}

// Round 2
// 119.585 us; speedup vs baseline: 1.1339x; 1.1339x over previous
//
#include <hip/hip_runtime.h>

typedef unsigned short u16;
typedef __bf16 bf16x8 __attribute__((ext_vector_type(8)));
typedef float  f32x4  __attribute__((ext_vector_type(4)));
typedef unsigned int   u32x4 __attribute__((ext_vector_type(4)));
typedef unsigned short u16x4 __attribute__((ext_vector_type(4)));

#define DEV __device__ __forceinline__

#define NB   16
#define TT   512
#define DD   256
#define HH   4
#define DKH  64
#define NLANG 10
#define FFD  1024

DEV u16 f2bf(float f) {
  unsigned int u = __builtin_bit_cast(unsigned int, f);
  return (u16)((u + 0x7fffu + ((u >> 16) & 1u)) >> 16);
}

DEV f32x4 zero4() { f32x4 z; z[0]=0.f; z[1]=0.f; z[2]=0.f; z[3]=0.f; return z; }

typedef __attribute__((address_space(1))) const unsigned int g_as1;
typedef __attribute__((address_space(3))) unsigned int l_as3;
// async global->LDS, 16B per lane; LDS dest = wave-uniform base + lane*16
DEV void load_lds16(const void* g, void* l) {
  __builtin_amdgcn_global_load_lds((g_as1*)g, (l_as3*)l, 16, 0, 0);
}

// ---------------- weight transpose + fp32->bf16 convert ----------------
// src: (z, R, C) f32   dst: (z, C, R) bf16   (dst[c][r] = src[r][c])
__global__ __launch_bounds__(256) void tconv_kernel(const float* __restrict__ src,
                                                    u16* __restrict__ dst,
                                                    int R, int C) {
  __shared__ u16 tile[32][33];
  const int z = blockIdx.z;
  const float* s = src + (size_t)z * R * C;
  u16* d = dst + (size_t)z * R * C;
  const int r0 = blockIdx.x * 32, c0 = blockIdx.y * 32;
  const int tx = threadIdx.x & 31, ty = threadIdx.x >> 5;  // ty in [0,8)
#pragma unroll
  for (int rr = 0; rr < 4; ++rr) {
    int r = ty + rr * 8;
    tile[r][tx] = f2bf(s[(size_t)(r0 + r) * C + c0 + tx]);
  }
  __syncthreads();
#pragma unroll
  for (int rr = 0; rr < 4; ++rr) {
    int cc = ty + rr * 8;
    d[(size_t)(c0 + cc) * R + r0 + tx] = tile[tx][cc];
  }
}

// ---------------- embed (x*sqrt(D)+PE) + LN1 ----------------
__global__ __launch_bounds__(256) void embed_ln_kernel(const float* __restrict__ x,
                                                       float* __restrict__ h0,
                                                       u16* __restrict__ hn,
                                                       const float* __restrict__ g,
                                                       const float* __restrict__ be,
                                                       const int* __restrict__ lids) {
  const int wave = threadIdx.x >> 6, lane = threadIdx.x & 63;
  const int row = blockIdx.x * 4 + wave;      // [0, 8192)
  const int b = row >> 9, t = row & 511;
  const int z = lids[b];
  const int c0 = lane * 4;
  const float4 xv = *(const float4*)(x + (size_t)row * DD + c0);
  const float kPE = -9.21034037197618f / 256.0f;  // -ln(10000)/D
  float div0 = __expf(kPE * (float)c0);
  float div1 = __expf(kPE * (float)(c0 + 2));
  float a0 = div0 * (float)t, a1 = div1 * (float)t;
  float h[4];
  h[0] = xv.x * 16.0f + sinf(a0);
  h[1] = xv.y * 16.0f + cosf(a0);
  h[2] = xv.z * 16.0f + sinf(a1);
  h[3] = xv.w * 16.0f + cosf(a1);
  float s = h[0] + h[1] + h[2] + h[3];
  float ss = h[0]*h[0] + h[1]*h[1] + h[2]*h[2] + h[3]*h[3];
#pragma unroll
  for (int d = 1; d < 64; d <<= 1) { s += __shfl_xor(s, d); ss += __shfl_xor(ss, d); }
  float mean = s * (1.0f / 256.0f);
  float var  = ss * (1.0f / 256.0f) - mean * mean;
  float rstd = rsqrtf(var + 1e-12f);
  *(float4*)(h0 + (size_t)row * DD + c0) = make_float4(h[0], h[1], h[2], h[3]);
  u16x4 o;
#pragma unroll
  for (int j = 0; j < 4; ++j)
    o[j] = f2bf((h[j] - mean) * rstd * g[z * DD + c0 + j] + be[z * DD + c0 + j]);
  *(u16x4*)(hn + (size_t)row * DD + c0) = o;
}

// ---------------- generic LN (f32 in; bf16 or f32 out) ----------------
template<int OUTF32>
__global__ __launch_bounds__(256) void ln_kernel(const float* __restrict__ in,
                                                 void* __restrict__ outp,
                                                 const float* __restrict__ g,
                                                 const float* __restrict__ be,
                                                 const int* __restrict__ lids) {
  const int wave = threadIdx.x >> 6, lane = threadIdx.x & 63;
  const int row = blockIdx.x * 4 + wave;
  const int b = row >> 9;
  const int z = lids[b];
  const int c0 = lane * 4;
  const float4 v = *(const float4*)(in + (size_t)row * DD + c0);
  float h[4] = {v.x, v.y, v.z, v.w};
  float s = h[0] + h[1] + h[2] + h[3];
  float ss = h[0]*h[0] + h[1]*h[1] + h[2]*h[2] + h[3]*h[3];
#pragma unroll
  for (int d = 1; d < 64; d <<= 1) { s += __shfl_xor(s, d); ss += __shfl_xor(ss, d); }
  float mean = s * (1.0f / 256.0f);
  float var  = ss * (1.0f / 256.0f) - mean * mean;
  float rstd = rsqrtf(var + 1e-12f);
  if (OUTF32) {
    float4 o;
    o.x = (h[0] - mean) * rstd * g[z * DD + c0 + 0] + be[z * DD + c0 + 0];
    o.y = (h[1] - mean) * rstd * g[z * DD + c0 + 1] + be[z * DD + c0 + 1];
    o.z = (h[2] - mean) * rstd * g[z * DD + c0 + 2] + be[z * DD + c0 + 2];
    o.w = (h[3] - mean) * rstd * g[z * DD + c0 + 3] + be[z * DD + c0 + 3];
    *(float4*)((float*)outp + (size_t)row * DD + c0) = o;
  } else {
    u16x4 o;
#pragma unroll
    for (int j = 0; j < 4; ++j)
      o[j] = f2bf((h[j] - mean) * rstd * g[z * DD + c0 + j] + be[z * DD + c0 + j]);
    *(u16x4*)((u16*)outp + (size_t)row * DD + c0) = o;
  }
}

// ---------------- GEMM core: C(128x128) = A(128xK) @ W^T(128xK)^T ----------------
DEV void gemm_tile(const u16* __restrict__ A, const u16* __restrict__ W, int K,
                   int m0, int n0, u16* Alds, u16* Blds, f32x4 acc[4][4]) {
  const int tid = threadIdx.x;
  const int lane = tid & 63;
  const int wave = tid >> 6;
  const int wm = wave >> 1, wn = wave & 1;
  const int l15 = lane & 15, lhi = lane >> 4;
  const int srow = tid >> 3;          // [0,32)
  const int sc8 = (tid & 7) << 3;     // 0..56
  for (int k0 = 0; k0 < K; k0 += 64) {
#pragma unroll
    for (int it = 0; it < 4; ++it) {
      int r = srow + it * 32;
      *(u32x4*)(Alds + r * 72 + sc8) = *(const u32x4*)(A + (size_t)(m0 + r) * K + k0 + sc8);
      *(u32x4*)(Blds + r * 72 + sc8) = *(const u32x4*)(W + (size_t)(n0 + r) * K + k0 + sc8);
    }
    __syncthreads();
#pragma unroll
    for (int ks = 0; ks < 2; ++ks) {
      const int kk = ks * 32 + lhi * 8;
      bf16x8 af[4], bfr[4];
#pragma unroll
      for (int m = 0; m < 4; ++m)
        af[m] = *(const bf16x8*)(Alds + (wm * 64 + m * 16 + l15) * 72 + kk);
#pragma unroll
      for (int n = 0; n < 4; ++n)
        bfr[n] = *(const bf16x8*)(Blds + (wn * 64 + n * 16 + l15) * 72 + kk);
#pragma unroll
      for (int m = 0; m < 4; ++m)
#pragma unroll
        for (int n = 0; n < 4; ++n)
          acc[m][n] = __builtin_amdgcn_mfma_f32_16x16x32_bf16(af[m], bfr[n], acc[m][n], 0, 0, 0);
    }
    __syncthreads();
  }
}

// EPI: 0 = bf16 out (+bias), 1 = bf16 out (+bias, relu), 2 = f32 out = res + acc + bias
template<int EPI>
__global__ __launch_bounds__(256) void gemm_kernel(const u16* __restrict__ A,
                                                   const u16* __restrict__ Wt,
                                                   const float* __restrict__ bias,
                                                   const float* __restrict__ res,
                                                   void* __restrict__ outp,
                                                   const int* __restrict__ lids,
                                                   int N, int K) {
  __shared__ u16 Alds[128 * 72];
  __shared__ u16 Blds[128 * 72];
  const int b = blockIdx.z;
  const int z = lids[b];
  const int m0 = blockIdx.y * 128, n0 = blockIdx.x * 128;
  f32x4 acc[4][4];
#pragma unroll
  for (int i = 0; i < 4; ++i)
#pragma unroll
    for (int j = 0; j < 4; ++j) acc[i][j] = zero4();
  gemm_tile(A + (size_t)b * TT * K, Wt + (size_t)z * N * K, K, m0, n0, Alds, Blds, acc);
  const int lane = threadIdx.x & 63, wave = threadIdx.x >> 6;
  const int wm = wave >> 1, wn = wave & 1;
  const int l15 = lane & 15, lhi = lane >> 4;
  float bvv[4];
#pragma unroll
  for (int n = 0; n < 4; ++n) bvv[n] = bias[(size_t)z * N + n0 + wn * 64 + n * 16 + l15];
#pragma unroll
  for (int m = 0; m < 4; ++m) {
    const int grow = m0 + wm * 64 + m * 16 + lhi * 4;
#pragma unroll
    for (int n = 0; n < 4; ++n) {
      const int gcol = n0 + wn * 64 + n * 16 + l15;
#pragma unroll
      for (int r = 0; r < 4; ++r) {
        float v = acc[m][n][r] + bvv[n];
        size_t idx = (size_t)b * TT * N + (size_t)(grow + r) * N + gcol;
        if (EPI == 0) ((u16*)outp)[idx] = f2bf(v);
        else if (EPI == 1) ((u16*)outp)[idx] = f2bf(v > 0.f ? v : 0.f);
        else ((float*)outp)[idx] = res[idx] + v;
      }
    }
  }
}

// QKV fused: grid (2,4,48). which = z>>4 selects Q/K/V; V stored transposed (B,H,DK,T).
__global__ __launch_bounds__(256) void gemm_qkv(const u16* __restrict__ A,
                                                const u16* __restrict__ wtq,
                                                const u16* __restrict__ wtk,
                                                const u16* __restrict__ wtv,
                                                const float* __restrict__ bq,
                                                const float* __restrict__ bk,
                                                const float* __restrict__ bv,
                                                u16* __restrict__ qo,
                                                u16* __restrict__ ko,
                                                u16* __restrict__ vto,
                                                const int* __restrict__ lids) {
  __shared__ u16 Alds[128 * 72];
  __shared__ u16 Blds[128 * 72];
  const int b = blockIdx.z & 15, which = blockIdx.z >> 4;
  const int z = lids[b];
  const u16* W = (which == 0) ? wtq : (which == 1) ? wtk : wtv;
  const float* bias = (which == 0) ? bq : (which == 1) ? bk : bv;
  const int m0 = blockIdx.y * 128, n0 = blockIdx.x * 128;
  f32x4 acc[4][4];
#pragma unroll
  for (int i = 0; i < 4; ++i)
#pragma unroll
    for (int j = 0; j < 4; ++j) acc[i][j] = zero4();
  gemm_tile(A + (size_t)b * TT * DD, W + (size_t)z * DD * DD, DD, m0, n0, Alds, Blds, acc);
  const int lane = threadIdx.x & 63, wave = threadIdx.x >> 6;
  const int wm = wave >> 1, wn = wave & 1;
  const int l15 = lane & 15, lhi = lane >> 4;
  float bvv[4];
#pragma unroll
  for (int n = 0; n < 4; ++n) bvv[n] = bias[(size_t)z * DD + n0 + wn * 64 + n * 16 + l15];
  if (which < 2) {
    u16* out = (which == 0) ? qo : ko;
#pragma unroll
    for (int m = 0; m < 4; ++m) {
      const int grow = m0 + wm * 64 + m * 16 + lhi * 4;
#pragma unroll
      for (int n = 0; n < 4; ++n) {
        const int gcol = n0 + wn * 64 + n * 16 + l15;
#pragma unroll
        for (int r = 0; r < 4; ++r)
          out[(size_t)b * TT * DD + (size_t)(grow + r) * DD + gcol] = f2bf(acc[m][n][r] + bvv[n]);
      }
    }
  } else {
#pragma unroll
    for (int m = 0; m < 4; ++m) {
      const int grow = m0 + wm * 64 + m * 16 + lhi * 4;  // t, multiple of 4
#pragma unroll
      for (int n = 0; n < 4; ++n) {
        const int gcol = n0 + wn * 64 + n * 16 + l15;    // feature = h*64+dk
        u16x4 pk;
#pragma unroll
        for (int r = 0; r < 4; ++r) pk[r] = f2bf(acc[m][n][r] + bvv[n]);
        *(u16x4*)(vto + (size_t)(b * HH + (gcol >> 6)) * DKH * TT + (size_t)(gcol & 63) * TT + grow) = pk;
      }
    }
  }
}

// ---------------- attention: flash-style, 8 waves = 2 kv-groups ----------------
// block = (qtile of 64 rows, head, batch); waves 0-3 = group 0 (even kv tiles),
// waves 4-7 = group 1 (odd kv tiles); KV tile = 128 columns; online softmax;
// K staged in LDS via pre-swizzled global_load_lds; combine (m,l,o) via LDS.
__global__ __launch_bounds__(512, 4) void attn_kernel(const u16* __restrict__ q,
                                                      const u16* __restrict__ k,
                                                      const u16* __restrict__ vt,
                                                      u16* __restrict__ ctx,
                                                      const int* __restrict__ lens) {
  __shared__ char smem[65536];
  u16* Kbuf = (u16*)smem;                 // [2][128*64] bf16, swizzled
  u16* Pbuf = (u16*)(smem + 32768);       // [2][64*128] bf16, swizzled
  float* Of = (float*)smem;               // reuse post-loop: [64][68] f32
  float* Ml = (float*)(smem + 32768);     // [64]
  float* Ll = (float*)(smem + 32768 + 256);

  const int qt = blockIdx.x, h = blockIdx.y, b = blockIdx.z;
  const int tid = threadIdx.x;
  const int lane = tid & 63, wave = tid >> 6;
  const int grp = wave >> 2, wq = wave & 3;
  const int l15 = lane & 15, lhi = lane >> 4;
  const int len = lens[b];
  const int nt = (len + 127) >> 7;        // 2..4
  const int iters = (nt + 1) >> 1;        // 1..2
  const int qrow0 = qt * 64 + wq * 16;
  const u16* qb = q + (size_t)b * TT * DD + h * DKH;
  const u16* kb = k + (size_t)b * TT * DD + h * DKH;
  const u16* vtb = vt + (size_t)(b * HH + h) * DKH * TT;

  u16* Kg = Kbuf + grp * (128 * 64);
  u16* Pg = Pbuf + grp * (64 * 128);

  // Q fragments (held in registers for the whole kernel)
  bf16x8 qf[2];
#pragma unroll
  for (int ks = 0; ks < 2; ++ks)
    qf[ks] = *(const bf16x8*)(qb + (size_t)(qrow0 + l15) * DD + ks * 32 + lhi * 8);

  // stage K tile t into Kg: linear LDS dest, pre-swizzled global source
  auto stage = [&](int t) {
    const int r0w = wq * 32;
#pragma unroll
    for (int j = 0; j < 4; ++j) {
      const int rb = r0w + j * 8;
      const int r = rb + (lane >> 3);
      const int s = (lane & 7) ^ (r & 7);
      load_lds16(kb + (size_t)(t * 128 + r) * DD + s * 8, Kg + rb * 64);
    }
  };

  float m[4] = {-1e30f, -1e30f, -1e30f, -1e30f};
  float l[4] = {0.f, 0.f, 0.f, 0.f};
  f32x4 o[4];
#pragma unroll
  for (int d0 = 0; d0 < 4; ++d0) o[d0] = zero4();

  stage(grp);  // prologue: tile 'grp' (0 or 1; nt>=2 so both valid)

  for (int i = 0; i < iters; ++i) {
    __syncthreads();  // staged K ready (vmcnt drained at barrier)
    const int t = 2 * i + grp;
    const bool active = (t < nt);
    if (active) {
      // ---- QK^T from LDS, masked online-softmax update, P -> LDS ----
      f32x4 S[8];
#pragma unroll
      for (int nb = 0; nb < 8; ++nb) {
        f32x4 a = zero4();
#pragma unroll
        for (int ks = 0; ks < 2; ++ks) {
          const int row = nb * 16 + l15;
          const int swz = (ks * 64 + lhi * 16) ^ ((row & 7) << 4);
          bf16x8 kf = *(const bf16x8*)(Kg + row * 64 + (swz >> 1));
          a = __builtin_amdgcn_mfma_f32_16x16x32_bf16(qf[ks], kf, a, 0, 0, 0);
        }
        S[nb] = a;
      }
      float tmax[4] = {-1e30f, -1e30f, -1e30f, -1e30f};
#pragma unroll
      for (int nb = 0; nb < 8; ++nb) {
        const int col = t * 128 + nb * 16 + l15;
#pragma unroll
        for (int r = 0; r < 4; ++r) {
          float v = S[nb][r] * 0.125f;
          v = (col < len) ? v : -1e30f;
          S[nb][r] = v;
          tmax[r] = fmaxf(tmax[r], v);
        }
      }
#pragma unroll
      for (int d = 1; d < 16; d <<= 1)
#pragma unroll
        for (int r = 0; r < 4; ++r) tmax[r] = fmaxf(tmax[r], __shfl_xor(tmax[r], d));
      float al[4];
#pragma unroll
      for (int r = 0; r < 4; ++r) {
        float mn = fmaxf(m[r], tmax[r]);
        al[r] = __expf(m[r] - mn);
        m[r] = mn;
      }
      float rs[4] = {0.f, 0.f, 0.f, 0.f};
#pragma unroll
      for (int nb = 0; nb < 8; ++nb) {
#pragma unroll
        for (int r = 0; r < 4; ++r) {
          float p = __expf(S[nb][r] - m[r]);
          rs[r] += p;
          const int lrow = wq * 16 + lhi * 4 + r;
          const int swzb = ((nb * 16 + l15) * 2) ^ ((lrow & 7) << 4);
          Pg[(lrow * 256 + swzb) >> 1] = f2bf(p);
        }
      }
#pragma unroll
      for (int d = 1; d < 16; d <<= 1)
#pragma unroll
        for (int r = 0; r < 4; ++r) rs[r] += __shfl_xor(rs[r], d);
#pragma unroll
      for (int r = 0; r < 4; ++r) l[r] = l[r] * al[r] + rs[r];
#pragma unroll
      for (int d0 = 0; d0 < 4; ++d0)
#pragma unroll
        for (int r = 0; r < 4; ++r) o[d0][r] *= al[r];
    }
    __syncthreads();  // all K reads done; P visible (same-wave rows anyway)
    if (t + 2 < nt) stage(t + 2);  // prefetch next tile for this group
    if (active) {
      // ---- O += P @ V (V^T layout (b,h,dk,t), direct from global/L2) ----
      const int arow = wq * 16 + l15;
#pragma unroll
      for (int ks = 0; ks < 4; ++ks) {
        const int swz = (ks * 64 + lhi * 16) ^ ((arow & 7) << 4);
        bf16x8 pf = *(const bf16x8*)(Pg + arow * 128 + (swz >> 1));
#pragma unroll
        for (int d0 = 0; d0 < 4; ++d0) {
          bf16x8 vf = *(const bf16x8*)(vtb + (size_t)(d0 * 16 + l15) * TT + t * 128 + ks * 32 + lhi * 8);
          o[d0] = __builtin_amdgcn_mfma_f32_16x16x32_bf16(pf, vf, o[d0], 0, 0, 0);
        }
      }
    }
  }

  // ---- combine the two kv-groups: group 1 publishes (m,l,o), group 0 merges ----
  __syncthreads();
  if (grp == 1) {
#pragma unroll
    for (int d0 = 0; d0 < 4; ++d0)
#pragma unroll
      for (int r = 0; r < 4; ++r)
        Of[(wq * 16 + lhi * 4 + r) * 68 + d0 * 16 + l15] = o[d0][r];
    if (l15 == 0) {
#pragma unroll
      for (int r = 0; r < 4; ++r) {
        Ml[wq * 16 + lhi * 4 + r] = m[r];
        Ll[wq * 16 + lhi * 4 + r] = l[r];
      }
    }
  }
  __syncthreads();
  if (grp == 0) {
    u16* cb = ctx + (size_t)b * TT * DD + h * DKH;
#pragma unroll
    for (int r = 0; r < 4; ++r) {
      const int lrow = wq * 16 + lhi * 4 + r;
      const float m1 = Ml[lrow], l1 = Ll[lrow];
      const float mn = fmaxf(m[r], m1);
      const float a0 = __expf(m[r] - mn), a1 = __expf(m1 - mn);
      const float linv = 1.0f / (l[r] * a0 + l1 * a1);
#pragma unroll
      for (int d0 = 0; d0 < 4; ++d0) {
        const float of = Of[lrow * 68 + d0 * 16 + l15];
        const float out = (o[d0][r] * a0 + of * a1) * linv;
        cb[(size_t)(qt * 64 + lrow) * DD + d0 * 16 + l15] = f2bf(out);
      }
    }
  }
}

// ---------------- host ----------------
extern "C" void kernel_launch(void* const* d_in, const int* in_sizes, int n_in,
                              void* d_out, int out_size, void* d_ws, size_t ws_size,
                              hipStream_t stream) {
  (void)in_sizes; (void)n_in; (void)out_size; (void)ws_size;
  const float* x    = (const float*)d_in[0];
  const int*   xlen = (const int*)d_in[1];
  const int*   lids = (const int*)d_in[2];
  const float* Wq = (const float*)d_in[3];
  const float* bq = (const float*)d_in[4];
  const float* Wk = (const float*)d_in[5];
  const float* bk = (const float*)d_in[6];
  const float* Wv = (const float*)d_in[7];
  const float* bv = (const float*)d_in[8];
  const float* Wo = (const float*)d_in[9];
  const float* bo = (const float*)d_in[10];
  const float* W1 = (const float*)d_in[11];
  const float* b1 = (const float*)d_in[12];
  const float* W2 = (const float*)d_in[13];
  const float* b2 = (const float*)d_in[14];
  const float* g1 = (const float*)d_in[15];
  const float* be1= (const float*)d_in[16];
  const float* g2 = (const float*)d_in[17];
  const float* be2= (const float*)d_in[18];
  const float* gf = (const float*)d_in[19];
  const float* bef= (const float*)d_in[20];

  char* ws = (char*)d_ws;
  size_t off = 0;
  auto alloc = [&](size_t bytes) -> void* {
    void* p = ws + off;
    off = (off + bytes + 255) & ~(size_t)255;
    return p;
  };
  u16* wtq = (u16*)alloc((size_t)NLANG * DD * DD * 2);
  u16* wtk = (u16*)alloc((size_t)NLANG * DD * DD * 2);
  u16* wtv = (u16*)alloc((size_t)NLANG * DD * DD * 2);
  u16* wto = (u16*)alloc((size_t)NLANG * DD * DD * 2);
  u16* wt1 = (u16*)alloc((size_t)NLANG * DD * FFD * 2);
  u16* wt2 = (u16*)alloc((size_t)NLANG * FFD * DD * 2);
  float* h0 = (float*)alloc((size_t)NB * TT * DD * 4);
  float* hc = (float*)alloc((size_t)NB * TT * DD * 4);
  u16* hn  = (u16*)alloc((size_t)NB * TT * DD * 2);
  u16* qb  = (u16*)alloc((size_t)NB * TT * DD * 2);
  u16* kb  = (u16*)alloc((size_t)NB * TT * DD * 2);
  u16* vtb = (u16*)alloc((size_t)NB * TT * DD * 2);
  u16* ctx = (u16*)alloc((size_t)NB * TT * DD * 2);
  u16* ffn = (u16*)alloc((size_t)NB * TT * FFD * 2);

  // weights -> bf16 transposed (N x K)
  tconv_kernel<<<dim3(8, 8, NLANG), 256, 0, stream>>>(Wq, wtq, DD, DD);
  tconv_kernel<<<dim3(8, 8, NLANG), 256, 0, stream>>>(Wk, wtk, DD, DD);
  tconv_kernel<<<dim3(8, 8, NLANG), 256, 0, stream>>>(Wv, wtv, DD, DD);
  tconv_kernel<<<dim3(8, 8, NLANG), 256, 0, stream>>>(Wo, wto, DD, DD);
  tconv_kernel<<<dim3(8, 32, NLANG), 256, 0, stream>>>(W1, wt1, DD, FFD);
  tconv_kernel<<<dim3(32, 8, NLANG), 256, 0, stream>>>(W2, wt2, FFD, DD);

  // h0 = x*16 + PE ; hn = LN1(h0)
  embed_ln_kernel<<<dim3(NB * TT / 4), 256, 0, stream>>>(x, h0, hn, g1, be1, lids);

  // QKV
  gemm_qkv<<<dim3(2, 4, 48), 256, 0, stream>>>(hn, wtq, wtk, wtv, bq, bk, bv, qb, kb, vtb, lids);

  // attention (flash-style, kv-split across 2 wave groups)
  attn_kernel<<<dim3(8, HH, NB), 512, 0, stream>>>(qb, kb, vtb, ctx, xlen);

  // h = h0 + ctx @ Wo + bo
  gemm_kernel<2><<<dim3(2, 4, NB), 256, 0, stream>>>(ctx, wto, bo, h0, hc, lids, DD, DD);

  // hn = LN2(h)
  ln_kernel<0><<<dim3(NB * TT / 4), 256, 0, stream>>>(hc, hn, g2, be2, lids);

  // ffn = relu(hn @ W1 + b1)
  gemm_kernel<1><<<dim3(8, 4, NB), 256, 0, stream>>>(hn, wt1, b1, nullptr, ffn, lids, FFD, DD);

  // h = h + ffn @ W2 + b2   (in-place residual)
  gemm_kernel<2><<<dim3(2, 4, NB), 256, 0, stream>>>(ffn, wt2, b2, hc, hc, lids, DD, FFD);

  // out = LNf(h)
  ln_kernel<1><<<dim3(NB * TT / 4), 256, 0, stream>>>(hc, d_out, gf, bef, lids);
}

// Round 3
// 105.835 us; speedup vs baseline: 1.2812x; 1.1299x over previous
//
#include <hip/hip_runtime.h>

typedef unsigned short u16;
typedef __bf16 bf16x8 __attribute__((ext_vector_type(8)));
typedef float  f32x4  __attribute__((ext_vector_type(4)));
typedef unsigned int   u32x4 __attribute__((ext_vector_type(4)));
typedef unsigned short u16x4 __attribute__((ext_vector_type(4)));

#define DEV __device__ __forceinline__

#define NB   16
#define TT   512
#define DD   256
#define HH   4
#define DKH  64
#define NLANG 10
#define FFD  1024

DEV u16 f2bf(float f) {
  unsigned int u = __builtin_bit_cast(unsigned int, f);
  return (u16)((u + 0x7fffu + ((u >> 16) & 1u)) >> 16);
}

DEV f32x4 zero4() { f32x4 z; z[0]=0.f; z[1]=0.f; z[2]=0.f; z[3]=0.f; return z; }

typedef __attribute__((address_space(1))) const unsigned int g_as1;
typedef __attribute__((address_space(3))) unsigned int l_as3;
// async global->LDS, 16B per lane; LDS dest = wave-uniform base + lane*16
DEV void load_lds16(const void* g, void* l) {
  __builtin_amdgcn_global_load_lds((g_as1*)g, (l_as3*)l, 16, 0, 0);
}

// ---------------- fused preprocessing ----------------
// blocks [0,7680): weight transpose+convert fp32->bf16 (dst[z][c][r] = src[z][r][c])
//   [0,2560): Wq/Wk/Wv/Wo (640 each: 10 z * 8x8 tiles of 32x32)
//   [2560,5120): W1 (10 z * 8x32 tiles)   [5120,7680): W2 (10 z * 32x8 tiles)
// blocks [7680,9728): embed (x*sqrt(D)+PE) + LN1 -> h0 (f32), hn (bf16)
__global__ __launch_bounds__(256) void pre_kernel(
    const float* __restrict__ Wq, const float* __restrict__ Wk,
    const float* __restrict__ Wv, const float* __restrict__ Wo,
    const float* __restrict__ W1, const float* __restrict__ W2,
    u16* __restrict__ wtq, u16* __restrict__ wtk, u16* __restrict__ wtv,
    u16* __restrict__ wto, u16* __restrict__ wt1, u16* __restrict__ wt2,
    const float* __restrict__ x, float* __restrict__ h0, u16* __restrict__ hn,
    const float* __restrict__ g, const float* __restrict__ be,
    const int* __restrict__ lids) {
  __shared__ u16 tile[32][33];
  const int bx = blockIdx.x;
  if (bx < 7680) {
    const float* src; u16* dst; int R, C, z, r0, c0;
    if (bx < 2560) {
      const int w = bx / 640, rem = bx % 640;
      src = (w == 0) ? Wq : (w == 1) ? Wk : (w == 2) ? Wv : Wo;
      dst = (w == 0) ? wtq : (w == 1) ? wtk : (w == 2) ? wtv : wto;
      R = 256; C = 256; z = rem >> 6;
      const int rc = rem & 63; r0 = (rc >> 3) * 32; c0 = (rc & 7) * 32;
    } else if (bx < 5120) {
      const int rem = bx - 2560; src = W1; dst = wt1; R = 256; C = 1024;
      z = rem >> 8; const int rc = rem & 255; r0 = (rc >> 5) * 32; c0 = (rc & 31) * 32;
    } else {
      const int rem = bx - 5120; src = W2; dst = wt2; R = 1024; C = 256;
      z = rem >> 8; const int rc = rem & 255; r0 = (rc >> 3) * 32; c0 = (rc & 7) * 32;
    }
    const float* s = src + (size_t)z * R * C;
    u16* d = dst + (size_t)z * R * C;
    const int tx = threadIdx.x & 31, ty = threadIdx.x >> 5;
#pragma unroll
    for (int rr = 0; rr < 4; ++rr) {
      const int r = ty + rr * 8;
      tile[r][tx] = f2bf(s[(size_t)(r0 + r) * C + c0 + tx]);
    }
    __syncthreads();
#pragma unroll
    for (int rr = 0; rr < 4; ++rr) {
      const int cc = ty + rr * 8;
      d[(size_t)(c0 + cc) * R + r0 + tx] = tile[tx][cc];
    }
  } else {
    const int wave = threadIdx.x >> 6, lane = threadIdx.x & 63;
    const int row = (bx - 7680) * 4 + wave;     // [0, 8192)
    const int b = row >> 9, t = row & 511;
    const int z = lids[b];
    const int c0 = lane * 4;
    const float4 xv = *(const float4*)(x + (size_t)row * DD + c0);
    const float kPE = -9.21034037197618f / 256.0f;  // -ln(10000)/D
    float div0 = __expf(kPE * (float)c0);
    float div1 = __expf(kPE * (float)(c0 + 2));
    float a0 = div0 * (float)t, a1 = div1 * (float)t;
    float h[4];
    h[0] = xv.x * 16.0f + sinf(a0);
    h[1] = xv.y * 16.0f + cosf(a0);
    h[2] = xv.z * 16.0f + sinf(a1);
    h[3] = xv.w * 16.0f + cosf(a1);
    float s = h[0] + h[1] + h[2] + h[3];
    float ss = h[0]*h[0] + h[1]*h[1] + h[2]*h[2] + h[3]*h[3];
#pragma unroll
    for (int d = 1; d < 64; d <<= 1) { s += __shfl_xor(s, d); ss += __shfl_xor(ss, d); }
    float mean = s * (1.0f / 256.0f);
    float var  = ss * (1.0f / 256.0f) - mean * mean;
    float rstd = rsqrtf(var + 1e-12f);
    *(float4*)(h0 + (size_t)row * DD + c0) = make_float4(h[0], h[1], h[2], h[3]);
    u16x4 o;
#pragma unroll
    for (int j = 0; j < 4; ++j)
      o[j] = f2bf((h[j] - mean) * rstd * g[z * DD + c0 + j] + be[z * DD + c0 + j]);
    *(u16x4*)(hn + (size_t)row * DD + c0) = o;
  }
}

// ---------------- generic LN (f32 in; bf16 or f32 out) ----------------
template<int OUTF32>
__global__ __launch_bounds__(256) void ln_kernel(const float* __restrict__ in,
                                                 void* __restrict__ outp,
                                                 const float* __restrict__ g,
                                                 const float* __restrict__ be,
                                                 const int* __restrict__ lids) {
  const int wave = threadIdx.x >> 6, lane = threadIdx.x & 63;
  const int row = blockIdx.x * 4 + wave;
  const int b = row >> 9;
  const int z = lids[b];
  const int c0 = lane * 4;
  const float4 v = *(const float4*)(in + (size_t)row * DD + c0);
  float h[4] = {v.x, v.y, v.z, v.w};
  float s = h[0] + h[1] + h[2] + h[3];
  float ss = h[0]*h[0] + h[1]*h[1] + h[2]*h[2] + h[3]*h[3];
#pragma unroll
  for (int d = 1; d < 64; d <<= 1) { s += __shfl_xor(s, d); ss += __shfl_xor(ss, d); }
  float mean = s * (1.0f / 256.0f);
  float var  = ss * (1.0f / 256.0f) - mean * mean;
  float rstd = rsqrtf(var + 1e-12f);
  if (OUTF32) {
    float4 o;
    o.x = (h[0] - mean) * rstd * g[z * DD + c0 + 0] + be[z * DD + c0 + 0];
    o.y = (h[1] - mean) * rstd * g[z * DD + c0 + 1] + be[z * DD + c0 + 1];
    o.z = (h[2] - mean) * rstd * g[z * DD + c0 + 2] + be[z * DD + c0 + 2];
    o.w = (h[3] - mean) * rstd * g[z * DD + c0 + 3] + be[z * DD + c0 + 3];
    *(float4*)((float*)outp + (size_t)row * DD + c0) = o;
  } else {
    u16x4 o;
#pragma unroll
    for (int j = 0; j < 4; ++j)
      o[j] = f2bf((h[j] - mean) * rstd * g[z * DD + c0 + j] + be[z * DD + c0 + j]);
    *(u16x4*)((u16*)outp + (size_t)row * DD + c0) = o;
  }
}

// ---------------- GEMM core 128x128 ----------------
DEV void gemm_tile(const u16* __restrict__ A, const u16* __restrict__ W, int K,
                   int m0, int n0, u16* Alds, u16* Blds, f32x4 acc[4][4]) {
  const int tid = threadIdx.x;
  const int lane = tid & 63;
  const int wave = tid >> 6;
  const int wm = wave >> 1, wn = wave & 1;
  const int l15 = lane & 15, lhi = lane >> 4;
  const int srow = tid >> 3;          // [0,32)
  const int sc8 = (tid & 7) << 3;     // 0..56
  for (int k0 = 0; k0 < K; k0 += 64) {
#pragma unroll
    for (int it = 0; it < 4; ++it) {
      int r = srow + it * 32;
      *(u32x4*)(Alds + r * 72 + sc8) = *(const u32x4*)(A + (size_t)(m0 + r) * K + k0 + sc8);
      *(u32x4*)(Blds + r * 72 + sc8) = *(const u32x4*)(W + (size_t)(n0 + r) * K + k0 + sc8);
    }
    __syncthreads();
#pragma unroll
    for (int ks = 0; ks < 2; ++ks) {
      const int kk = ks * 32 + lhi * 8;
      bf16x8 af[4], bfr[4];
#pragma unroll
      for (int m = 0; m < 4; ++m)
        af[m] = *(const bf16x8*)(Alds + (wm * 64 + m * 16 + l15) * 72 + kk);
#pragma unroll
      for (int n = 0; n < 4; ++n)
        bfr[n] = *(const bf16x8*)(Blds + (wn * 64 + n * 16 + l15) * 72 + kk);
#pragma unroll
      for (int m = 0; m < 4; ++m)
#pragma unroll
        for (int n = 0; n < 4; ++n)
          acc[m][n] = __builtin_amdgcn_mfma_f32_16x16x32_bf16(af[m], bfr[n], acc[m][n], 0, 0, 0);
    }
    __syncthreads();
  }
}

// EPI: 1 = bf16 out (+bias, relu)
template<int EPI>
__global__ __launch_bounds__(256) void gemm_kernel(const u16* __restrict__ A,
                                                   const u16* __restrict__ Wt,
                                                   const float* __restrict__ bias,
                                                   const float* __restrict__ res,
                                                   void* __restrict__ outp,
                                                   const int* __restrict__ lids,
                                                   int N, int K) {
  __shared__ u16 Alds[128 * 72];
  __shared__ u16 Blds[128 * 72];
  const int b = blockIdx.z;
  const int z = lids[b];
  const int m0 = blockIdx.y * 128, n0 = blockIdx.x * 128;
  f32x4 acc[4][4];
#pragma unroll
  for (int i = 0; i < 4; ++i)
#pragma unroll
    for (int j = 0; j < 4; ++j) acc[i][j] = zero4();
  gemm_tile(A + (size_t)b * TT * K, Wt + (size_t)z * N * K, K, m0, n0, Alds, Blds, acc);
  const int lane = threadIdx.x & 63, wave = threadIdx.x >> 6;
  const int wm = wave >> 1, wn = wave & 1;
  const int l15 = lane & 15, lhi = lane >> 4;
  float bvv[4];
#pragma unroll
  for (int n = 0; n < 4; ++n) bvv[n] = bias[(size_t)z * N + n0 + wn * 64 + n * 16 + l15];
#pragma unroll
  for (int m = 0; m < 4; ++m) {
    const int grow = m0 + wm * 64 + m * 16 + lhi * 4;
#pragma unroll
    for (int n = 0; n < 4; ++n) {
      const int gcol = n0 + wn * 64 + n * 16 + l15;
#pragma unroll
      for (int r = 0; r < 4; ++r) {
        float v = acc[m][n][r] + bvv[n];
        size_t idx = (size_t)b * TT * N + (size_t)(grow + r) * N + gcol;
        if (EPI == 1) ((u16*)outp)[idx] = f2bf(v > 0.f ? v : 0.f);
        else ((u16*)outp)[idx] = f2bf(v);
      }
    }
  }
}

// ---------------- GEMM 128x64 tiles (for small-N GEMMs: Wo, FFN2) ----------------
// out f32 = res + acc + bias; 4 waves, each 32 rows x 64 cols (acc[2][4])
__global__ __launch_bounds__(256) void gemm64_kernel(const u16* __restrict__ A,
                                                     const u16* __restrict__ Wt,
                                                     const float* __restrict__ bias,
                                                     const float* __restrict__ res,
                                                     float* __restrict__ outp,
                                                     const int* __restrict__ lids,
                                                     int N, int K) {
  __shared__ u16 Alds[128 * 72];
  __shared__ u16 Blds[64 * 72];
  const int b = blockIdx.z;
  const int z = lids[b];
  const int m0 = blockIdx.y * 128, n0 = blockIdx.x * 64;
  const int tid = threadIdx.x, lane = tid & 63, wave = tid >> 6;
  const int l15 = lane & 15, lhi = lane >> 4;
  const int srow = tid >> 3, sc8 = (tid & 7) << 3;
  const u16* Ab = A + (size_t)b * TT * K;
  const u16* Wb = Wt + (size_t)z * N * K;
  f32x4 acc[2][4];
#pragma unroll
  for (int i = 0; i < 2; ++i)
#pragma unroll
    for (int j = 0; j < 4; ++j) acc[i][j] = zero4();
  for (int k0 = 0; k0 < K; k0 += 64) {
#pragma unroll
    for (int it = 0; it < 4; ++it) {
      int r = srow + it * 32;
      *(u32x4*)(Alds + r * 72 + sc8) = *(const u32x4*)(Ab + (size_t)(m0 + r) * K + k0 + sc8);
    }
#pragma unroll
    for (int it = 0; it < 2; ++it) {
      int r = srow + it * 32;
      *(u32x4*)(Blds + r * 72 + sc8) = *(const u32x4*)(Wb + (size_t)(n0 + r) * K + k0 + sc8);
    }
    __syncthreads();
#pragma unroll
    for (int ks = 0; ks < 2; ++ks) {
      const int kk = ks * 32 + lhi * 8;
      bf16x8 af[2], bfr[4];
#pragma unroll
      for (int m = 0; m < 2; ++m)
        af[m] = *(const bf16x8*)(Alds + (wave * 32 + m * 16 + l15) * 72 + kk);
#pragma unroll
      for (int n = 0; n < 4; ++n)
        bfr[n] = *(const bf16x8*)(Blds + (n * 16 + l15) * 72 + kk);
#pragma unroll
      for (int m = 0; m < 2; ++m)
#pragma unroll
        for (int n = 0; n < 4; ++n)
          acc[m][n] = __builtin_amdgcn_mfma_f32_16x16x32_bf16(af[m], bfr[n], acc[m][n], 0, 0, 0);
    }
    __syncthreads();
  }
  float bvv[4];
#pragma unroll
  for (int n = 0; n < 4; ++n) bvv[n] = bias[(size_t)z * N + n0 + n * 16 + l15];
#pragma unroll
  for (int m = 0; m < 2; ++m) {
    const int grow = m0 + wave * 32 + m * 16 + lhi * 4;
#pragma unroll
    for (int n = 0; n < 4; ++n) {
      const int gcol = n0 + n * 16 + l15;
#pragma unroll
      for (int r = 0; r < 4; ++r) {
        size_t idx = (size_t)b * TT * N + (size_t)(grow + r) * N + gcol;
        outp[idx] = res[idx] + acc[m][n][r] + bvv[n];
      }
    }
  }
}

// QKV fused: grid (2,4,48). which = z>>4 selects Q/K/V; V stored transposed (B,H,DK,T).
__global__ __launch_bounds__(256) void gemm_qkv(const u16* __restrict__ A,
                                                const u16* __restrict__ wtq,
                                                const u16* __restrict__ wtk,
                                                const u16* __restrict__ wtv,
                                                const float* __restrict__ bq,
                                                const float* __restrict__ bk,
                                                const float* __restrict__ bv,
                                                u16* __restrict__ qo,
                                                u16* __restrict__ ko,
                                                u16* __restrict__ vto,
                                                const int* __restrict__ lids) {
  __shared__ u16 Alds[128 * 72];
  __shared__ u16 Blds[128 * 72];
  const int b = blockIdx.z & 15, which = blockIdx.z >> 4;
  const int z = lids[b];
  const u16* W = (which == 0) ? wtq : (which == 1) ? wtk : wtv;
  const float* bias = (which == 0) ? bq : (which == 1) ? bk : bv;
  const int m0 = blockIdx.y * 128, n0 = blockIdx.x * 128;
  f32x4 acc[4][4];
#pragma unroll
  for (int i = 0; i < 4; ++i)
#pragma unroll
    for (int j = 0; j < 4; ++j) acc[i][j] = zero4();
  gemm_tile(A + (size_t)b * TT * DD, W + (size_t)z * DD * DD, DD, m0, n0, Alds, Blds, acc);
  const int lane = threadIdx.x & 63, wave = threadIdx.x >> 6;
  const int wm = wave >> 1, wn = wave & 1;
  const int l15 = lane & 15, lhi = lane >> 4;
  float bvv[4];
#pragma unroll
  for (int n = 0; n < 4; ++n) bvv[n] = bias[(size_t)z * DD + n0 + wn * 64 + n * 16 + l15];
  if (which < 2) {
    u16* out = (which == 0) ? qo : ko;
#pragma unroll
    for (int m = 0; m < 4; ++m) {
      const int grow = m0 + wm * 64 + m * 16 + lhi * 4;
#pragma unroll
      for (int n = 0; n < 4; ++n) {
        const int gcol = n0 + wn * 64 + n * 16 + l15;
#pragma unroll
        for (int r = 0; r < 4; ++r)
          out[(size_t)b * TT * DD + (size_t)(grow + r) * DD + gcol] = f2bf(acc[m][n][r] + bvv[n]);
      }
    }
  } else {
#pragma unroll
    for (int m = 0; m < 4; ++m) {
      const int grow = m0 + wm * 64 + m * 16 + lhi * 4;  // t, multiple of 4
#pragma unroll
      for (int n = 0; n < 4; ++n) {
        const int gcol = n0 + wn * 64 + n * 16 + l15;    // feature = h*64+dk
        u16x4 pk;
#pragma unroll
        for (int r = 0; r < 4; ++r) pk[r] = f2bf(acc[m][n][r] + bvv[n]);
        *(u16x4*)(vto + (size_t)(b * HH + (gcol >> 6)) * DKH * TT + (size_t)(gcol & 63) * TT + grow) = pk;
      }
    }
  }
}

// ---------------- attention: flash-style, 8 waves = 2 kv-groups ----------------
// softmax in base-2 domain (v_exp_f32 = 2^x): scores pre-scaled by 0.125*log2(e)
__global__ __launch_bounds__(512, 4) void attn_kernel(const u16* __restrict__ q,
                                                      const u16* __restrict__ k,
                                                      const u16* __restrict__ vt,
                                                      u16* __restrict__ ctx,
                                                      const int* __restrict__ lens) {
  __shared__ char smem[65536];
  u16* Kbuf = (u16*)smem;                 // [2][128*64] bf16, swizzled
  u16* Pbuf = (u16*)(smem + 32768);       // [2][64*128] bf16, swizzled
  float* Of = (float*)smem;               // reuse post-loop: [64][68] f32
  float* Ml = (float*)(smem + 32768);     // [64]
  float* Ll = (float*)(smem + 32768 + 256);

  const int qt = blockIdx.x, h = blockIdx.y, b = blockIdx.z;
  const int tid = threadIdx.x;
  const int lane = tid & 63, wave = tid >> 6;
  const int grp = wave >> 2, wq = wave & 3;
  const int l15 = lane & 15, lhi = lane >> 4;
  const int len = lens[b];
  const int nt = (len + 127) >> 7;        // 2..4
  const int iters = (nt + 1) >> 1;        // 1..2
  const int qrow0 = qt * 64 + wq * 16;
  const u16* qb = q + (size_t)b * TT * DD + h * DKH;
  const u16* kb = k + (size_t)b * TT * DD + h * DKH;
  const u16* vtb = vt + (size_t)(b * HH + h) * DKH * TT;
  const float SC = 0.125f * 1.4426950408889634f;  // /sqrt(DK) * log2(e)

  u16* Kg = Kbuf + grp * (128 * 64);
  u16* Pg = Pbuf + grp * (64 * 128);

  bf16x8 qf[2];
#pragma unroll
  for (int ks = 0; ks < 2; ++ks)
    qf[ks] = *(const bf16x8*)(qb + (size_t)(qrow0 + l15) * DD + ks * 32 + lhi * 8);

  auto stage = [&](int t) {
    const int r0w = wq * 32;
#pragma unroll
    for (int j = 0; j < 4; ++j) {
      const int rb = r0w + j * 8;
      const int r = rb + (lane >> 3);
      const int s = (lane & 7) ^ (r & 7);
      load_lds16(kb + (size_t)(t * 128 + r) * DD + s * 8, Kg + rb * 64);
    }
  };

  float m[4] = {-1e30f, -1e30f, -1e30f, -1e30f};
  float l[4] = {0.f, 0.f, 0.f, 0.f};
  f32x4 o[4];
#pragma unroll
  for (int d0 = 0; d0 < 4; ++d0) o[d0] = zero4();

  stage(grp);  // prologue

  for (int i = 0; i < iters; ++i) {
    __syncthreads();
    const int t = 2 * i + grp;
    const bool active = (t < nt);
    if (active) {
      f32x4 S[8];
#pragma unroll
      for (int nb = 0; nb < 8; ++nb) {
        f32x4 a = zero4();
#pragma unroll
        for (int ks = 0; ks < 2; ++ks) {
          const int row = nb * 16 + l15;
          const int swz = (ks * 64 + lhi * 16) ^ ((row & 7) << 4);
          bf16x8 kf = *(const bf16x8*)(Kg + row * 64 + (swz >> 1));
          a = __builtin_amdgcn_mfma_f32_16x16x32_bf16(qf[ks], kf, a, 0, 0, 0);
        }
        S[nb] = a;
      }
      float tmax[4] = {-1e30f, -1e30f, -1e30f, -1e30f};
#pragma unroll
      for (int nb = 0; nb < 8; ++nb) {
        const int col = t * 128 + nb * 16 + l15;
#pragma unroll
        for (int r = 0; r < 4; ++r) {
          float v = S[nb][r] * SC;
          v = (col < len) ? v : -1e30f;
          S[nb][r] = v;
          tmax[r] = fmaxf(tmax[r], v);
        }
      }
#pragma unroll
      for (int d = 1; d < 16; d <<= 1)
#pragma unroll
        for (int r = 0; r < 4; ++r) tmax[r] = fmaxf(tmax[r], __shfl_xor(tmax[r], d));
      float al[4];
#pragma unroll
      for (int r = 0; r < 4; ++r) {
        float mn = fmaxf(m[r], tmax[r]);
        al[r] = exp2f(m[r] - mn);
        m[r] = mn;
      }
      float rs[4] = {0.f, 0.f, 0.f, 0.f};
#pragma unroll
      for (int nb = 0; nb < 8; ++nb) {
#pragma unroll
        for (int r = 0; r < 4; ++r) {
          float p = exp2f(S[nb][r] - m[r]);
          rs[r] += p;
          const int lrow = wq * 16 + lhi * 4 + r;
          const int swzb = ((nb * 16 + l15) * 2) ^ ((lrow & 7) << 4);
          Pg[(lrow * 256 + swzb) >> 1] = f2bf(p);
        }
      }
#pragma unroll
      for (int d = 1; d < 16; d <<= 1)
#pragma unroll
        for (int r = 0; r < 4; ++r) rs[r] += __shfl_xor(rs[r], d);
#pragma unroll
      for (int r = 0; r < 4; ++r) l[r] = l[r] * al[r] + rs[r];
#pragma unroll
      for (int d0 = 0; d0 < 4; ++d0)
#pragma unroll
        for (int r = 0; r < 4; ++r) o[d0][r] *= al[r];
    }
    __syncthreads();
    if (t + 2 < nt) stage(t + 2);
    if (active) {
      const int arow = wq * 16 + l15;
#pragma unroll
      for (int ks = 0; ks < 4; ++ks) {
        const int swz = (ks * 64 + lhi * 16) ^ ((arow & 7) << 4);
        bf16x8 pf = *(const bf16x8*)(Pg + arow * 128 + (swz >> 1));
#pragma unroll
        for (int d0 = 0; d0 < 4; ++d0) {
          bf16x8 vf = *(const bf16x8*)(vtb + (size_t)(d0 * 16 + l15) * TT + t * 128 + ks * 32 + lhi * 8);
          o[d0] = __builtin_amdgcn_mfma_f32_16x16x32_bf16(pf, vf, o[d0], 0, 0, 0);
        }
      }
    }
  }

  __syncthreads();
  if (grp == 1) {
#pragma unroll
    for (int d0 = 0; d0 < 4; ++d0)
#pragma unroll
      for (int r = 0; r < 4; ++r)
        Of[(wq * 16 + lhi * 4 + r) * 68 + d0 * 16 + l15] = o[d0][r];
    if (l15 == 0) {
#pragma unroll
      for (int r = 0; r < 4; ++r) {
        Ml[wq * 16 + lhi * 4 + r] = m[r];
        Ll[wq * 16 + lhi * 4 + r] = l[r];
      }
    }
  }
  __syncthreads();
  if (grp == 0) {
    u16* cb = ctx + (size_t)b * TT * DD + h * DKH;
#pragma unroll
    for (int r = 0; r < 4; ++r) {
      const int lrow = wq * 16 + lhi * 4 + r;
      const float m1 = Ml[lrow], l1 = Ll[lrow];
      const float mn = fmaxf(m[r], m1);
      const float a0 = exp2f(m[r] - mn), a1 = exp2f(m1 - mn);
      const float linv = 1.0f / (l[r] * a0 + l1 * a1);
#pragma unroll
      for (int d0 = 0; d0 < 4; ++d0) {
        const float of = Of[lrow * 68 + d0 * 16 + l15];
        const float out = (o[d0][r] * a0 + of * a1) * linv;
        cb[(size_t)(qt * 64 + lrow) * DD + d0 * 16 + l15] = f2bf(out);
      }
    }
  }
}

// ---------------- host ----------------
extern "C" void kernel_launch(void* const* d_in, const int* in_sizes, int n_in,
                              void* d_out, int out_size, void* d_ws, size_t ws_size,
                              hipStream_t stream) {
  (void)in_sizes; (void)n_in; (void)out_size; (void)ws_size;
  const float* x    = (const float*)d_in[0];
  const int*   xlen = (const int*)d_in[1];
  const int*   lids = (const int*)d_in[2];
  const float* Wq = (const float*)d_in[3];
  const float* bq = (const float*)d_in[4];
  const float* Wk = (const float*)d_in[5];
  const float* bk = (const float*)d_in[6];
  const float* Wv = (const float*)d_in[7];
  const float* bv = (const float*)d_in[8];
  const float* Wo = (const float*)d_in[9];
  const float* bo = (const float*)d_in[10];
  const float* W1 = (const float*)d_in[11];
  const float* b1 = (const float*)d_in[12];
  const float* W2 = (const float*)d_in[13];
  const float* b2 = (const float*)d_in[14];
  const float* g1 = (const float*)d_in[15];
  const float* be1= (const float*)d_in[16];
  const float* g2 = (const float*)d_in[17];
  const float* be2= (const float*)d_in[18];
  const float* gf = (const float*)d_in[19];
  const float* bef= (const float*)d_in[20];

  char* ws = (char*)d_ws;
  size_t off = 0;
  auto alloc = [&](size_t bytes) -> void* {
    void* p = ws + off;
    off = (off + bytes + 255) & ~(size_t)255;
    return p;
  };
  u16* wtq = (u16*)alloc((size_t)NLANG * DD * DD * 2);
  u16* wtk = (u16*)alloc((size_t)NLANG * DD * DD * 2);
  u16* wtv = (u16*)alloc((size_t)NLANG * DD * DD * 2);
  u16* wto = (u16*)alloc((size_t)NLANG * DD * DD * 2);
  u16* wt1 = (u16*)alloc((size_t)NLANG * DD * FFD * 2);
  u16* wt2 = (u16*)alloc((size_t)NLANG * FFD * DD * 2);
  float* h0 = (float*)alloc((size_t)NB * TT * DD * 4);
  float* hc = (float*)alloc((size_t)NB * TT * DD * 4);
  u16* hn  = (u16*)alloc((size_t)NB * TT * DD * 2);
  u16* qb  = (u16*)alloc((size_t)NB * TT * DD * 2);
  u16* kb  = (u16*)alloc((size_t)NB * TT * DD * 2);
  u16* vtb = (u16*)alloc((size_t)NB * TT * DD * 2);
  u16* ctx = (u16*)alloc((size_t)NB * TT * DD * 2);
  u16* ffn = (u16*)alloc((size_t)NB * TT * FFD * 2);

  // fused: all weight transposes + embed+LN1
  pre_kernel<<<dim3(7680 + 2048), 256, 0, stream>>>(
      Wq, Wk, Wv, Wo, W1, W2, wtq, wtk, wtv, wto, wt1, wt2,
      x, h0, hn, g1, be1, lids);

  // QKV
  gemm_qkv<<<dim3(2, 4, 48), 256, 0, stream>>>(hn, wtq, wtk, wtv, bq, bk, bv, qb, kb, vtb, lids);

  // attention
  attn_kernel<<<dim3(8, HH, NB), 512, 0, stream>>>(qb, kb, vtb, ctx, xlen);

  // h = h0 + ctx @ Wo + bo   (128x64 tiles -> 256 blocks)
  gemm64_kernel<<<dim3(4, 4, NB), 256, 0, stream>>>(ctx, wto, bo, h0, hc, lids, DD, DD);

  // hn = LN2(h)
  ln_kernel<0><<<dim3(NB * TT / 4), 256, 0, stream>>>(hc, hn, g2, be2, lids);

  // ffn = relu(hn @ W1 + b1)
  gemm_kernel<1><<<dim3(8, 4, NB), 256, 0, stream>>>(hn, wt1, b1, nullptr, ffn, lids, FFD, DD);

  // h = h + ffn @ W2 + b2    (128x64 tiles, in-place residual)
  gemm64_kernel<<<dim3(4, 4, NB), 256, 0, stream>>>(ffn, wt2, b2, hc, hc, lids, DD, FFD);

  // out = LNf(h)
  ln_kernel<1><<<dim3(NB * TT / 4), 256, 0, stream>>>(hc, d_out, gf, bef, lids);
}

// Round 4
// 105.241 us; speedup vs baseline: 1.2885x; 1.0056x over previous
//
#include <hip/hip_runtime.h>

typedef unsigned short u16;
typedef __bf16 bf16x8 __attribute__((ext_vector_type(8)));
typedef float  f32x4  __attribute__((ext_vector_type(4)));
typedef unsigned int   u32x4 __attribute__((ext_vector_type(4)));
typedef unsigned short u16x4 __attribute__((ext_vector_type(4)));

#define DEV __device__ __forceinline__

#define NB   16
#define TT   512
#define DD   256
#define HH   4
#define DKH  64
#define NLANG 10
#define FFD  1024

DEV u16 f2bf(float f) {
  unsigned int u = __builtin_bit_cast(unsigned int, f);
  return (u16)((u + 0x7fffu + ((u >> 16) & 1u)) >> 16);
}

DEV f32x4 zero4() { f32x4 z; z[0]=0.f; z[1]=0.f; z[2]=0.f; z[3]=0.f; return z; }

typedef __attribute__((address_space(1))) const unsigned int g_as1;
typedef __attribute__((address_space(3))) unsigned int l_as3;
// async global->LDS, 16B per lane; LDS dest = wave-uniform base + lane*16
DEV void load_lds16(const void* g, void* l) {
  __builtin_amdgcn_global_load_lds((g_as1*)g, (l_as3*)l, 16, 0, 0);
}

// swizzled fragment read from a linear [rows][64] bf16 LDS tile.
// slot = 16B-group index within the row (0..7); involution: slot ^= row&7.
DEV bf16x8 lds_frag(const u16* lds, int row, int slot) {
  return *(const bf16x8*)(lds + row * 64 + ((slot ^ (row & 7)) << 3));
}

// ---------------- fused preprocessing ----------------
// blocks [0,7680): weight transpose+convert fp32->bf16 (dst[z][c][r] = src[z][r][c])
// blocks [7680,9728): embed (x*sqrt(D)+PE) + LN1 -> h0 (f32), hn (bf16)
__global__ __launch_bounds__(256) void pre_kernel(
    const float* __restrict__ Wq, const float* __restrict__ Wk,
    const float* __restrict__ Wv, const float* __restrict__ Wo,
    const float* __restrict__ W1, const float* __restrict__ W2,
    u16* __restrict__ wtq, u16* __restrict__ wtk, u16* __restrict__ wtv,
    u16* __restrict__ wto, u16* __restrict__ wt1, u16* __restrict__ wt2,
    const float* __restrict__ x, float* __restrict__ h0, u16* __restrict__ hn,
    const float* __restrict__ g, const float* __restrict__ be,
    const int* __restrict__ lids) {
  __shared__ u16 tile[32][33];
  const int bx = blockIdx.x;
  if (bx < 7680) {
    const float* src; u16* dst; int R, C, z, r0, c0;
    if (bx < 2560) {
      const int w = bx / 640, rem = bx % 640;
      src = (w == 0) ? Wq : (w == 1) ? Wk : (w == 2) ? Wv : Wo;
      dst = (w == 0) ? wtq : (w == 1) ? wtk : (w == 2) ? wtv : wto;
      R = 256; C = 256; z = rem >> 6;
      const int rc = rem & 63; r0 = (rc >> 3) * 32; c0 = (rc & 7) * 32;
    } else if (bx < 5120) {
      const int rem = bx - 2560; src = W1; dst = wt1; R = 256; C = 1024;
      z = rem >> 8; const int rc = rem & 255; r0 = (rc >> 5) * 32; c0 = (rc & 31) * 32;
    } else {
      const int rem = bx - 5120; src = W2; dst = wt2; R = 1024; C = 256;
      z = rem >> 8; const int rc = rem & 255; r0 = (rc >> 3) * 32; c0 = (rc & 7) * 32;
    }
    // skip languages not present in this batch
    bool used = false;
#pragma unroll
    for (int i = 0; i < NB; ++i) used |= (lids[i] == z);
    if (!used) return;
    const float* s = src + (size_t)z * R * C;
    u16* d = dst + (size_t)z * R * C;
    const int tx = threadIdx.x & 31, ty = threadIdx.x >> 5;
#pragma unroll
    for (int rr = 0; rr < 4; ++rr) {
      const int r = ty + rr * 8;
      tile[r][tx] = f2bf(s[(size_t)(r0 + r) * C + c0 + tx]);
    }
    __syncthreads();
#pragma unroll
    for (int rr = 0; rr < 4; ++rr) {
      const int cc = ty + rr * 8;
      d[(size_t)(c0 + cc) * R + r0 + tx] = tile[tx][cc];
    }
  } else {
    const int wave = threadIdx.x >> 6, lane = threadIdx.x & 63;
    const int row = (bx - 7680) * 4 + wave;     // [0, 8192)
    const int b = row >> 9, t = row & 511;
    const int z = lids[b];
    const int c0 = lane * 4;
    const float4 xv = *(const float4*)(x + (size_t)row * DD + c0);
    const float kPE = -9.21034037197618f / 256.0f;  // -ln(10000)/D
    float div0 = __expf(kPE * (float)c0);
    float div1 = __expf(kPE * (float)(c0 + 2));
    float a0 = div0 * (float)t, a1 = div1 * (float)t;
    float h[4];
    h[0] = xv.x * 16.0f + sinf(a0);
    h[1] = xv.y * 16.0f + cosf(a0);
    h[2] = xv.z * 16.0f + sinf(a1);
    h[3] = xv.w * 16.0f + cosf(a1);
    float s = h[0] + h[1] + h[2] + h[3];
    float ss = h[0]*h[0] + h[1]*h[1] + h[2]*h[2] + h[3]*h[3];
#pragma unroll
    for (int d = 1; d < 64; d <<= 1) { s += __shfl_xor(s, d); ss += __shfl_xor(ss, d); }
    float mean = s * (1.0f / 256.0f);
    float var  = ss * (1.0f / 256.0f) - mean * mean;
    float rstd = rsqrtf(var + 1e-12f);
    *(float4*)(h0 + (size_t)row * DD + c0) = make_float4(h[0], h[1], h[2], h[3]);
    u16x4 o;
#pragma unroll
    for (int j = 0; j < 4; ++j)
      o[j] = f2bf((h[j] - mean) * rstd * g[z * DD + c0 + j] + be[z * DD + c0 + j]);
    *(u16x4*)(hn + (size_t)row * DD + c0) = o;
  }
}

// ---------------- generic LN (f32 in; bf16 or f32 out) ----------------
template<int OUTF32>
__global__ __launch_bounds__(256) void ln_kernel(const float* __restrict__ in,
                                                 void* __restrict__ outp,
                                                 const float* __restrict__ g,
                                                 const float* __restrict__ be,
                                                 const int* __restrict__ lids) {
  const int wave = threadIdx.x >> 6, lane = threadIdx.x & 63;
  const int row = blockIdx.x * 4 + wave;
  const int b = row >> 9;
  const int z = lids[b];
  const int c0 = lane * 4;
  const float4 v = *(const float4*)(in + (size_t)row * DD + c0);
  float h[4] = {v.x, v.y, v.z, v.w};
  float s = h[0] + h[1] + h[2] + h[3];
  float ss = h[0]*h[0] + h[1]*h[1] + h[2]*h[2] + h[3]*h[3];
#pragma unroll
  for (int d = 1; d < 64; d <<= 1) { s += __shfl_xor(s, d); ss += __shfl_xor(ss, d); }
  float mean = s * (1.0f / 256.0f);
  float var  = ss * (1.0f / 256.0f) - mean * mean;
  float rstd = rsqrtf(var + 1e-12f);
  if (OUTF32) {
    float4 o;
    o.x = (h[0] - mean) * rstd * g[z * DD + c0 + 0] + be[z * DD + c0 + 0];
    o.y = (h[1] - mean) * rstd * g[z * DD + c0 + 1] + be[z * DD + c0 + 1];
    o.z = (h[2] - mean) * rstd * g[z * DD + c0 + 2] + be[z * DD + c0 + 2];
    o.w = (h[3] - mean) * rstd * g[z * DD + c0 + 3] + be[z * DD + c0 + 3];
    *(float4*)((float*)outp + (size_t)row * DD + c0) = o;
  } else {
    u16x4 o;
#pragma unroll
    for (int j = 0; j < 4; ++j)
      o[j] = f2bf((h[j] - mean) * rstd * g[z * DD + c0 + j] + be[z * DD + c0 + j]);
    *(u16x4*)((u16*)outp + (size_t)row * DD + c0) = o;
  }
}

// ---------------- GEMM core 128x128, m97-style ----------------
// global_load_lds width-16 into linear [128][64] LDS, source-side XOR swizzle;
// 2 barriers per K-step; swizzled ds_read_b128 fragment reads.
DEV void gemm_tile(const u16* __restrict__ A, const u16* __restrict__ W, int K,
                   int m0, int n0, u16* Alds, u16* Blds, f32x4 acc[4][4]) {
  const int tid = threadIdx.x;
  const int lane = tid & 63;
  const int wave = tid >> 6;
  const int wm = wave >> 1, wn = wave & 1;
  const int l15 = lane & 15, lhi = lane >> 4;
  const int lr = lane >> 3, lsl = lane & 7;
  const u16* srcA[4]; const u16* srcB[4];
#pragma unroll
  for (int j = 0; j < 4; ++j) {
    const int r = wave * 32 + j * 8 + lr;
    srcA[j] = A + (size_t)(m0 + r) * K + ((lsl ^ (r & 7)) << 3);
    srcB[j] = W + (size_t)(n0 + r) * K + ((lsl ^ (r & 7)) << 3);
  }
  for (int k0 = 0; k0 < K; k0 += 64) {
#pragma unroll
    for (int j = 0; j < 4; ++j) {
      load_lds16(srcA[j] + k0, Alds + (wave * 32 + j * 8) * 64);
      load_lds16(srcB[j] + k0, Blds + (wave * 32 + j * 8) * 64);
    }
    __syncthreads();
#pragma unroll
    for (int ks = 0; ks < 2; ++ks) {
      const int slot = ks * 4 + lhi;
      bf16x8 af[4], bfr[4];
#pragma unroll
      for (int m = 0; m < 4; ++m)
        af[m] = lds_frag(Alds, wm * 64 + m * 16 + l15, slot);
#pragma unroll
      for (int n = 0; n < 4; ++n)
        bfr[n] = lds_frag(Blds, wn * 64 + n * 16 + l15, slot);
#pragma unroll
      for (int m = 0; m < 4; ++m)
#pragma unroll
        for (int n = 0; n < 4; ++n)
          acc[m][n] = __builtin_amdgcn_mfma_f32_16x16x32_bf16(af[m], bfr[n], acc[m][n], 0, 0, 0);
    }
    __syncthreads();
  }
}

// EPI: 1 = bf16 out (+bias, relu)
template<int EPI>
__global__ __launch_bounds__(256) void gemm_kernel(const u16* __restrict__ A,
                                                   const u16* __restrict__ Wt,
                                                   const float* __restrict__ bias,
                                                   const float* __restrict__ res,
                                                   void* __restrict__ outp,
                                                   const int* __restrict__ lids,
                                                   int N, int K) {
  __shared__ u16 Alds[128 * 64];
  __shared__ u16 Blds[128 * 64];
  const int b = blockIdx.z;
  const int z = lids[b];
  const int m0 = blockIdx.y * 128, n0 = blockIdx.x * 128;
  f32x4 acc[4][4];
#pragma unroll
  for (int i = 0; i < 4; ++i)
#pragma unroll
    for (int j = 0; j < 4; ++j) acc[i][j] = zero4();
  gemm_tile(A + (size_t)b * TT * K, Wt + (size_t)z * N * K, K, m0, n0, Alds, Blds, acc);
  const int lane = threadIdx.x & 63, wave = threadIdx.x >> 6;
  const int wm = wave >> 1, wn = wave & 1;
  const int l15 = lane & 15, lhi = lane >> 4;
  float bvv[4];
#pragma unroll
  for (int n = 0; n < 4; ++n) bvv[n] = bias[(size_t)z * N + n0 + wn * 64 + n * 16 + l15];
#pragma unroll
  for (int m = 0; m < 4; ++m) {
    const int grow = m0 + wm * 64 + m * 16 + lhi * 4;
#pragma unroll
    for (int n = 0; n < 4; ++n) {
      const int gcol = n0 + wn * 64 + n * 16 + l15;
#pragma unroll
      for (int r = 0; r < 4; ++r) {
        float v = acc[m][n][r] + bvv[n];
        size_t idx = (size_t)b * TT * N + (size_t)(grow + r) * N + gcol;
        if (EPI == 1) ((u16*)outp)[idx] = f2bf(v > 0.f ? v : 0.f);
        else ((u16*)outp)[idx] = f2bf(v);
      }
    }
  }
}

// ---------------- GEMM 128x64 tiles (Wo, FFN2), m97-style staging ----------------
__global__ __launch_bounds__(256) void gemm64_kernel(const u16* __restrict__ A,
                                                     const u16* __restrict__ Wt,
                                                     const float* __restrict__ bias,
                                                     const float* __restrict__ res,
                                                     float* __restrict__ outp,
                                                     const int* __restrict__ lids,
                                                     int N, int K) {
  __shared__ u16 Alds[128 * 64];
  __shared__ u16 Blds[64 * 64];
  const int b = blockIdx.z;
  const int z = lids[b];
  const int m0 = blockIdx.y * 128, n0 = blockIdx.x * 64;
  const int tid = threadIdx.x, lane = tid & 63, wave = tid >> 6;
  const int l15 = lane & 15, lhi = lane >> 4;
  const int lr = lane >> 3, lsl = lane & 7;
  const u16* Ab = A + (size_t)b * TT * K;
  const u16* Wb = Wt + (size_t)z * N * K;
  const u16* srcA[4]; const u16* srcB[2];
#pragma unroll
  for (int j = 0; j < 4; ++j) {
    const int r = wave * 32 + j * 8 + lr;
    srcA[j] = Ab + (size_t)(m0 + r) * K + ((lsl ^ (r & 7)) << 3);
  }
#pragma unroll
  for (int j = 0; j < 2; ++j) {
    const int r = wave * 16 + j * 8 + lr;
    srcB[j] = Wb + (size_t)(n0 + r) * K + ((lsl ^ (r & 7)) << 3);
  }
  f32x4 acc[2][4];
#pragma unroll
  for (int i = 0; i < 2; ++i)
#pragma unroll
    for (int j = 0; j < 4; ++j) acc[i][j] = zero4();
  for (int k0 = 0; k0 < K; k0 += 64) {
#pragma unroll
    for (int j = 0; j < 4; ++j)
      load_lds16(srcA[j] + k0, Alds + (wave * 32 + j * 8) * 64);
#pragma unroll
    for (int j = 0; j < 2; ++j)
      load_lds16(srcB[j] + k0, Blds + (wave * 16 + j * 8) * 64);
    __syncthreads();
#pragma unroll
    for (int ks = 0; ks < 2; ++ks) {
      const int slot = ks * 4 + lhi;
      bf16x8 af[2], bfr[4];
#pragma unroll
      for (int m = 0; m < 2; ++m)
        af[m] = lds_frag(Alds, wave * 32 + m * 16 + l15, slot);
#pragma unroll
      for (int n = 0; n < 4; ++n)
        bfr[n] = lds_frag(Blds, n * 16 + l15, slot);
#pragma unroll
      for (int m = 0; m < 2; ++m)
#pragma unroll
        for (int n = 0; n < 4; ++n)
          acc[m][n] = __builtin_amdgcn_mfma_f32_16x16x32_bf16(af[m], bfr[n], acc[m][n], 0, 0, 0);
    }
    __syncthreads();
  }
  float bvv[4];
#pragma unroll
  for (int n = 0; n < 4; ++n) bvv[n] = bias[(size_t)z * N + n0 + n * 16 + l15];
#pragma unroll
  for (int m = 0; m < 2; ++m) {
    const int grow = m0 + wave * 32 + m * 16 + lhi * 4;
#pragma unroll
    for (int n = 0; n < 4; ++n) {
      const int gcol = n0 + n * 16 + l15;
#pragma unroll
      for (int r = 0; r < 4; ++r) {
        size_t idx = (size_t)b * TT * N + (size_t)(grow + r) * N + gcol;
        outp[idx] = res[idx] + acc[m][n][r] + bvv[n];
      }
    }
  }
}

// QKV fused: grid (2,4,48). which = z>>4 selects Q/K/V; V stored transposed (B,H,DK,T).
__global__ __launch_bounds__(256) void gemm_qkv(const u16* __restrict__ A,
                                                const u16* __restrict__ wtq,
                                                const u16* __restrict__ wtk,
                                                const u16* __restrict__ wtv,
                                                const float* __restrict__ bq,
                                                const float* __restrict__ bk,
                                                const float* __restrict__ bv,
                                                u16* __restrict__ qo,
                                                u16* __restrict__ ko,
                                                u16* __restrict__ vto,
                                                const int* __restrict__ lids) {
  __shared__ u16 Alds[128 * 64];
  __shared__ u16 Blds[128 * 64];
  const int b = blockIdx.z & 15, which = blockIdx.z >> 4;
  const int z = lids[b];
  const u16* W = (which == 0) ? wtq : (which == 1) ? wtk : wtv;
  const float* bias = (which == 0) ? bq : (which == 1) ? bk : bv;
  const int m0 = blockIdx.y * 128, n0 = blockIdx.x * 128;
  f32x4 acc[4][4];
#pragma unroll
  for (int i = 0; i < 4; ++i)
#pragma unroll
    for (int j = 0; j < 4; ++j) acc[i][j] = zero4();
  gemm_tile(A + (size_t)b * TT * DD, W + (size_t)z * DD * DD, DD, m0, n0, Alds, Blds, acc);
  const int lane = threadIdx.x & 63, wave = threadIdx.x >> 6;
  const int wm = wave >> 1, wn = wave & 1;
  const int l15 = lane & 15, lhi = lane >> 4;
  float bvv[4];
#pragma unroll
  for (int n = 0; n < 4; ++n) bvv[n] = bias[(size_t)z * DD + n0 + wn * 64 + n * 16 + l15];
  if (which < 2) {
    u16* out = (which == 0) ? qo : ko;
#pragma unroll
    for (int m = 0; m < 4; ++m) {
      const int grow = m0 + wm * 64 + m * 16 + lhi * 4;
#pragma unroll
      for (int n = 0; n < 4; ++n) {
        const int gcol = n0 + wn * 64 + n * 16 + l15;
#pragma unroll
        for (int r = 0; r < 4; ++r)
          out[(size_t)b * TT * DD + (size_t)(grow + r) * DD + gcol] = f2bf(acc[m][n][r] + bvv[n]);
      }
    }
  } else {
#pragma unroll
    for (int m = 0; m < 4; ++m) {
      const int grow = m0 + wm * 64 + m * 16 + lhi * 4;  // t, multiple of 4
#pragma unroll
      for (int n = 0; n < 4; ++n) {
        const int gcol = n0 + wn * 64 + n * 16 + l15;    // feature = h*64+dk
        u16x4 pk;
#pragma unroll
        for (int r = 0; r < 4; ++r) pk[r] = f2bf(acc[m][n][r] + bvv[n]);
        *(u16x4*)(vto + (size_t)(b * HH + (gcol >> 6)) * DKH * TT + (size_t)(gcol & 63) * TT + grow) = pk;
      }
    }
  }
}

// ---------------- attention: flash-style, 8 waves = 2 kv-groups ----------------
__global__ __launch_bounds__(512, 4) void attn_kernel(const u16* __restrict__ q,
                                                      const u16* __restrict__ k,
                                                      const u16* __restrict__ vt,
                                                      u16* __restrict__ ctx,
                                                      const int* __restrict__ lens) {
  __shared__ char smem[65536];
  u16* Kbuf = (u16*)smem;                 // [2][128*64] bf16, swizzled
  u16* Pbuf = (u16*)(smem + 32768);       // [2][64*128] bf16, swizzled
  float* Of = (float*)smem;               // reuse post-loop: [64][68] f32
  float* Ml = (float*)(smem + 32768);     // [64]
  float* Ll = (float*)(smem + 32768 + 256);

  const int qt = blockIdx.x, h = blockIdx.y, b = blockIdx.z;
  const int tid = threadIdx.x;
  const int lane = tid & 63, wave = tid >> 6;
  const int grp = wave >> 2, wq = wave & 3;
  const int l15 = lane & 15, lhi = lane >> 4;
  const int len = lens[b];
  const int nt = (len + 127) >> 7;        // 2..4
  const int iters = (nt + 1) >> 1;        // 1..2
  const int qrow0 = qt * 64 + wq * 16;
  const u16* qb = q + (size_t)b * TT * DD + h * DKH;
  const u16* kb = k + (size_t)b * TT * DD + h * DKH;
  const u16* vtb = vt + (size_t)(b * HH + h) * DKH * TT;
  const float SC = 0.125f * 1.4426950408889634f;  // /sqrt(DK) * log2(e)

  u16* Kg = Kbuf + grp * (128 * 64);
  u16* Pg = Pbuf + grp * (64 * 128);

  bf16x8 qf[2];
#pragma unroll
  for (int ks = 0; ks < 2; ++ks)
    qf[ks] = *(const bf16x8*)(qb + (size_t)(qrow0 + l15) * DD + ks * 32 + lhi * 8);

  auto stage = [&](int t) {
    const int r0w = wq * 32;
#pragma unroll
    for (int j = 0; j < 4; ++j) {
      const int rb = r0w + j * 8;
      const int r = rb + (lane >> 3);
      const int s = (lane & 7) ^ (r & 7);
      load_lds16(kb + (size_t)(t * 128 + r) * DD + s * 8, Kg + rb * 64);
    }
  };

  float m[4] = {-1e30f, -1e30f, -1e30f, -1e30f};
  float l[4] = {0.f, 0.f, 0.f, 0.f};
  f32x4 o[4];
#pragma unroll
  for (int d0 = 0; d0 < 4; ++d0) o[d0] = zero4();

  stage(grp);  // prologue

  for (int i = 0; i < iters; ++i) {
    __syncthreads();
    const int t = 2 * i + grp;
    const bool active = (t < nt);
    if (active) {
      f32x4 S[8];
#pragma unroll
      for (int nb = 0; nb < 8; ++nb) {
        f32x4 a = zero4();
#pragma unroll
        for (int ks = 0; ks < 2; ++ks) {
          const int row = nb * 16 + l15;
          const int swz = (ks * 64 + lhi * 16) ^ ((row & 7) << 4);
          bf16x8 kf = *(const bf16x8*)(Kg + row * 64 + (swz >> 1));
          a = __builtin_amdgcn_mfma_f32_16x16x32_bf16(qf[ks], kf, a, 0, 0, 0);
        }
        S[nb] = a;
      }
      float tmax[4] = {-1e30f, -1e30f, -1e30f, -1e30f};
#pragma unroll
      for (int nb = 0; nb < 8; ++nb) {
        const int col = t * 128 + nb * 16 + l15;
#pragma unroll
        for (int r = 0; r < 4; ++r) {
          float v = S[nb][r] * SC;
          v = (col < len) ? v : -1e30f;
          S[nb][r] = v;
          tmax[r] = fmaxf(tmax[r], v);
        }
      }
#pragma unroll
      for (int d = 1; d < 16; d <<= 1)
#pragma unroll
        for (int r = 0; r < 4; ++r) tmax[r] = fmaxf(tmax[r], __shfl_xor(tmax[r], d));
      float al[4];
#pragma unroll
      for (int r = 0; r < 4; ++r) {
        float mn = fmaxf(m[r], tmax[r]);
        al[r] = exp2f(m[r] - mn);
        m[r] = mn;
      }
      float rs[4] = {0.f, 0.f, 0.f, 0.f};
#pragma unroll
      for (int nb = 0; nb < 8; ++nb) {
#pragma unroll
        for (int r = 0; r < 4; ++r) {
          float p = exp2f(S[nb][r] - m[r]);
          rs[r] += p;
          const int lrow = wq * 16 + lhi * 4 + r;
          const int swzb = ((nb * 16 + l15) * 2) ^ ((lrow & 7) << 4);
          Pg[(lrow * 256 + swzb) >> 1] = f2bf(p);
        }
      }
#pragma unroll
      for (int d = 1; d < 16; d <<= 1)
#pragma unroll
        for (int r = 0; r < 4; ++r) rs[r] += __shfl_xor(rs[r], d);
#pragma unroll
      for (int r = 0; r < 4; ++r) l[r] = l[r] * al[r] + rs[r];
#pragma unroll
      for (int d0 = 0; d0 < 4; ++d0)
#pragma unroll
        for (int r = 0; r < 4; ++r) o[d0][r] *= al[r];
    }
    __syncthreads();
    if (t + 2 < nt) stage(t + 2);
    if (active) {
      const int arow = wq * 16 + l15;
#pragma unroll
      for (int ks = 0; ks < 4; ++ks) {
        const int swz = (ks * 64 + lhi * 16) ^ ((arow & 7) << 4);
        bf16x8 pf = *(const bf16x8*)(Pg + arow * 128 + (swz >> 1));
#pragma unroll
        for (int d0 = 0; d0 < 4; ++d0) {
          bf16x8 vf = *(const bf16x8*)(vtb + (size_t)(d0 * 16 + l15) * TT + t * 128 + ks * 32 + lhi * 8);
          o[d0] = __builtin_amdgcn_mfma_f32_16x16x32_bf16(pf, vf, o[d0], 0, 0, 0);
        }
      }
    }
  }

  __syncthreads();
  if (grp == 1) {
#pragma unroll
    for (int d0 = 0; d0 < 4; ++d0)
#pragma unroll
      for (int r = 0; r < 4; ++r)
        Of[(wq * 16 + lhi * 4 + r) * 68 + d0 * 16 + l15] = o[d0][r];
    if (l15 == 0) {
#pragma unroll
      for (int r = 0; r < 4; ++r) {
        Ml[wq * 16 + lhi * 4 + r] = m[r];
        Ll[wq * 16 + lhi * 4 + r] = l[r];
      }
    }
  }
  __syncthreads();
  if (grp == 0) {
    u16* cb = ctx + (size_t)b * TT * DD + h * DKH;
#pragma unroll
    for (int r = 0; r < 4; ++r) {
      const int lrow = wq * 16 + lhi * 4 + r;
      const float m1 = Ml[lrow], l1 = Ll[lrow];
      const float mn = fmaxf(m[r], m1);
      const float a0 = exp2f(m[r] - mn), a1 = exp2f(m1 - mn);
      const float linv = 1.0f / (l[r] * a0 + l1 * a1);
#pragma unroll
      for (int d0 = 0; d0 < 4; ++d0) {
        const float of = Of[lrow * 68 + d0 * 16 + l15];
        const float out = (o[d0][r] * a0 + of * a1) * linv;
        cb[(size_t)(qt * 64 + lrow) * DD + d0 * 16 + l15] = f2bf(out);
      }
    }
  }
}

// ---------------- host ----------------
extern "C" void kernel_launch(void* const* d_in, const int* in_sizes, int n_in,
                              void* d_out, int out_size, void* d_ws, size_t ws_size,
                              hipStream_t stream) {
  (void)in_sizes; (void)n_in; (void)out_size; (void)ws_size;
  const float* x    = (const float*)d_in[0];
  const int*   xlen = (const int*)d_in[1];
  const int*   lids = (const int*)d_in[2];
  const float* Wq = (const float*)d_in[3];
  const float* bq = (const float*)d_in[4];
  const float* Wk = (const float*)d_in[5];
  const float* bk = (const float*)d_in[6];
  const float* Wv = (const float*)d_in[7];
  const float* bv = (const float*)d_in[8];
  const float* Wo = (const float*)d_in[9];
  const float* bo = (const float*)d_in[10];
  const float* W1 = (const float*)d_in[11];
  const float* b1 = (const float*)d_in[12];
  const float* W2 = (const float*)d_in[13];
  const float* b2 = (const float*)d_in[14];
  const float* g1 = (const float*)d_in[15];
  const float* be1= (const float*)d_in[16];
  const float* g2 = (const float*)d_in[17];
  const float* be2= (const float*)d_in[18];
  const float* gf = (const float*)d_in[19];
  const float* bef= (const float*)d_in[20];

  char* ws = (char*)d_ws;
  size_t off = 0;
  auto alloc = [&](size_t bytes) -> void* {
    void* p = ws + off;
    off = (off + bytes + 255) & ~(size_t)255;
    return p;
  };
  u16* wtq = (u16*)alloc((size_t)NLANG * DD * DD * 2);
  u16* wtk = (u16*)alloc((size_t)NLANG * DD * DD * 2);
  u16* wtv = (u16*)alloc((size_t)NLANG * DD * DD * 2);
  u16* wto = (u16*)alloc((size_t)NLANG * DD * DD * 2);
  u16* wt1 = (u16*)alloc((size_t)NLANG * DD * FFD * 2);
  u16* wt2 = (u16*)alloc((size_t)NLANG * FFD * DD * 2);
  float* h0 = (float*)alloc((size_t)NB * TT * DD * 4);
  float* hc = (float*)alloc((size_t)NB * TT * DD * 4);
  u16* hn  = (u16*)alloc((size_t)NB * TT * DD * 2);
  u16* qb  = (u16*)alloc((size_t)NB * TT * DD * 2);
  u16* kb  = (u16*)alloc((size_t)NB * TT * DD * 2);
  u16* vtb = (u16*)alloc((size_t)NB * TT * DD * 2);
  u16* ctx = (u16*)alloc((size_t)NB * TT * DD * 2);
  u16* ffn = (u16*)alloc((size_t)NB * TT * FFD * 2);

  // fused: all weight transposes (used langs only) + embed+LN1
  pre_kernel<<<dim3(7680 + 2048), 256, 0, stream>>>(
      Wq, Wk, Wv, Wo, W1, W2, wtq, wtk, wtv, wto, wt1, wt2,
      x, h0, hn, g1, be1, lids);

  // QKV
  gemm_qkv<<<dim3(2, 4, 48), 256, 0, stream>>>(hn, wtq, wtk, wtv, bq, bk, bv, qb, kb, vtb, lids);

  // attention
  attn_kernel<<<dim3(8, HH, NB), 512, 0, stream>>>(qb, kb, vtb, ctx, xlen);

  // h = h0 + ctx @ Wo + bo   (128x64 tiles -> 256 blocks)
  gemm64_kernel<<<dim3(4, 4, NB), 256, 0, stream>>>(ctx, wto, bo, h0, hc, lids, DD, DD);

  // hn = LN2(h)
  ln_kernel<0><<<dim3(NB * TT / 4), 256, 0, stream>>>(hc, hn, g2, be2, lids);

  // ffn = relu(hn @ W1 + b1)
  gemm_kernel<1><<<dim3(8, 4, NB), 256, 0, stream>>>(hn, wt1, b1, nullptr, ffn, lids, FFD, DD);

  // h = h + ffn @ W2 + b2    (128x64 tiles, in-place residual)
  gemm64_kernel<<<dim3(4, 4, NB), 256, 0, stream>>>(ffn, wt2, b2, hc, hc, lids, DD, FFD);

  // out = LNf(h)
  ln_kernel<1><<<dim3(NB * TT / 4), 256, 0, stream>>>(hc, d_out, gf, bef, lids);
}